// Round 2
// baseline (663.510 us; speedup 1.0000x reference)
//
#include <hip/hip_runtime.h>
#include <stdint.h>

#define S_ 128
#define R_ 256
#define CM_ 256
#define H_ 8
#define CA_ 32
#define CZ_ 128
#define HC_ 256   // H*CA

typedef unsigned short u16;
typedef __bf16 bf16x8 __attribute__((ext_vector_type(8)));
typedef float f32x4 __attribute__((ext_vector_type(4)));

__device__ __forceinline__ float bf2f(u16 u){ unsigned v = ((unsigned)u) << 16; float f; __builtin_memcpy(&f, &v, 4); return f; }
__device__ __forceinline__ u16 f2bf(float f){ unsigned v; __builtin_memcpy(&v, &f, 4); v += 0x7fffu + ((v >> 16) & 1u); return (u16)(v >> 16); }

// ---------------- weight transpose fp32->bf16 (+ optional scale) ----------------
__global__ void transpose_w(const float* __restrict__ in, u16* __restrict__ out,
                            int K, int N, float scale){
  int idx = blockIdx.x * 256 + threadIdx.x;
  if(idx >= K * N) return;
  int k = idx / N, n = idx - k * N;
  out[(long long)n * K + k] = f2bf(in[idx] * scale);
}

// ---------------- LayerNorm over last dim C=256, fp32 in -> bf16 out ----------------
__global__ __launch_bounds__(256) void ln_kernel(const float* __restrict__ in, const float* __restrict__ w,
                          const float* __restrict__ b, u16* __restrict__ out){
  int wv = threadIdx.x >> 6, lane = threadIdx.x & 63;
  long long row = (long long)blockIdx.x * 4 + wv;
  const float* rp = in + row * CM_;
  float v[4]; float s = 0.f;
  #pragma unroll
  for(int i = 0; i < 4; i++){ v[i] = rp[lane + i * 64]; s += v[i]; }
  for(int mo = 32; mo; mo >>= 1) s += __shfl_xor(s, mo, 64);
  float mu = s * (1.f / CM_);
  float s2 = 0.f;
  #pragma unroll
  for(int i = 0; i < 4; i++){ float d = v[i] - mu; s2 += d * d; }
  for(int mo = 32; mo; mo >>= 1) s2 += __shfl_xor(s2, mo, 64);
  float rstd = rsqrtf(s2 * (1.f / CM_) + 1e-5f);
  u16* op = out + row * CM_;
  #pragma unroll
  for(int i = 0; i < 4; i++){
    int c = lane + i * 64;
    op[c] = f2bf((v[i] - mu) * rstd * w[c] + b[c]);
  }
}

// ---------------- pair bias: LN(z) @ wb -> bias[h][q][k] (fp32) ----------------
__global__ __launch_bounds__(256) void pair_bias_kernel(const float* __restrict__ z, const float* __restrict__ lnw,
                                 const float* __restrict__ lnb, const float* __restrict__ wb,
                                 float* __restrict__ bias){
  int wv = threadIdx.x >> 6, lane = threadIdx.x & 63;
  long long row = (long long)blockIdx.x * 4 + wv;        // q*256 + k
  const float* rp = z + row * CZ_;
  float v0 = rp[lane], v1 = rp[lane + 64];
  float s = v0 + v1;
  for(int mo = 32; mo; mo >>= 1) s += __shfl_xor(s, mo, 64);
  float mu = s * (1.f / CZ_);
  float d0 = v0 - mu, d1 = v1 - mu;
  float s2 = d0 * d0 + d1 * d1;
  for(int mo = 32; mo; mo >>= 1) s2 += __shfl_xor(s2, mo, 64);
  float rstd = rsqrtf(s2 * (1.f / CZ_) + 1e-5f);
  float x0 = d0 * rstd * lnw[lane] + lnb[lane];
  float x1 = d1 * rstd * lnw[lane + 64] + lnb[lane + 64];
  float acc[8];
  #pragma unroll
  for(int h = 0; h < 8; h++)
    acc[h] = x0 * wb[lane * 8 + h] + x1 * wb[(lane + 64) * 8 + h];
  for(int mo = 32; mo; mo >>= 1){
    #pragma unroll
    for(int h = 0; h < 8; h++) acc[h] += __shfl_xor(acc[h], mo, 64);
  }
  if(lane < 8) bias[(long long)lane * (R_ * R_) + row] = acc[lane];
}

// ---------------- generic MFMA GEMM: out[M][N] = act(A[M][K] @ W[K][N] + bias) ----------------
// A is internal bf16; Wt is W transposed [N][K] bf16; bias/res fp32; out bf16 or fp32.
template<bool GMUL, bool SIG, bool RELU, bool RES, bool F32OUT>
__global__ __launch_bounds__(256) void gemm_kernel(
    const u16* __restrict__ A, const u16* __restrict__ A2,
    const u16* __restrict__ Wt, const float* __restrict__ bias,
    const float* __restrict__ res, void* __restrict__ outv,
    int M, int N, int K){
  __shared__ __attribute__((aligned(16))) unsigned char Al[64 * 64];
  __shared__ __attribute__((aligned(16))) unsigned char Bl[64 * 64];
  const int t = threadIdx.x;
  const int wv = t >> 6, lane = t & 63, l15 = lane & 15, l4 = lane >> 4;
  const long long m0 = (long long)blockIdx.y * 64;
  const int n0 = blockIdx.x * 64;
  const int ms = (wv >> 1) * 32, ns = (wv & 1) * 32;
  const int arow = t >> 2, achk = t & 3;
  f32x4 acc[2][2] = {};
  for(int kk = 0; kk < K; kk += 32){
    {
      long long ga = (m0 + arow) * (long long)K + kk + achk * 8;
      int4 av = *(const int4*)(A + ga);
      if(GMUL){
        int4 gv = *(const int4*)(A2 + ga);
        u16* ap = (u16*)&av; const u16* gp = (const u16*)&gv;
        #pragma unroll
        for(int j = 0; j < 8; j++) ap[j] = f2bf(bf2f(ap[j]) * bf2f(gp[j]));
      }
      *(int4*)(Al + ((arow * 64 + achk * 16) ^ ((arow & 7) << 4))) = av;
      long long gb = (long long)(n0 + arow) * K + kk + achk * 8;
      *(int4*)(Bl + ((arow * 64 + achk * 16) ^ ((arow & 7) << 4))) = *(const int4*)(Wt + gb);
    }
    __syncthreads();
    bf16x8 af[2], bfr[2];
    #pragma unroll
    for(int mt = 0; mt < 2; mt++){
      int r = ms + mt * 16 + l15;
      af[mt] = *(const bf16x8*)(Al + ((r * 64 + l4 * 16) ^ ((r & 7) << 4)));
    }
    #pragma unroll
    for(int nt = 0; nt < 2; nt++){
      int r = ns + nt * 16 + l15;
      bfr[nt] = *(const bf16x8*)(Bl + ((r * 64 + l4 * 16) ^ ((r & 7) << 4)));
    }
    #pragma unroll
    for(int mt = 0; mt < 2; mt++)
      #pragma unroll
      for(int nt = 0; nt < 2; nt++)
        acc[mt][nt] = __builtin_amdgcn_mfma_f32_16x16x32_bf16(af[mt], bfr[nt], acc[mt][nt], 0, 0, 0);
    __syncthreads();
  }
  #pragma unroll
  for(int mt = 0; mt < 2; mt++)
    #pragma unroll
    for(int nt = 0; nt < 2; nt++)
      #pragma unroll
      for(int r = 0; r < 4; r++){
        long long mrow = m0 + ms + mt * 16 + l4 * 4 + r;
        int ncol = n0 + ns + nt * 16 + l15;
        float vv = acc[mt][nt][r] + (bias ? bias[ncol] : 0.f);
        if(SIG)  vv = 1.f / (1.f + __expf(-vv));
        if(RELU) vv = vv > 0.f ? vv : 0.f;
        if(RES)  vv += res[mrow * N + ncol];
        if(F32OUT) ((float*)outv)[mrow * N + ncol] = vv;
        else       ((u16*)outv)[mrow * N + ncol] = f2bf(vv);
      }
}

// ---------------- fused attention per (outer, h): softmax(Q K^T + bias + mask) V ----------------
// Token addressing: elem(tok,c) = base + tok*tstride + c, base = outer*obase_mul + h*CA.
template<int L, bool HAS_BIAS>
__global__ __launch_bounds__(256) void atten_kernel(
    const u16* __restrict__ qg, const u16* __restrict__ kg, const u16* __restrict__ vg,
    const float* __restrict__ bias, const float* __restrict__ mask, u16* __restrict__ og,
    long long obase_mul, long long tstride, long long mbase_mul, int mstride){
  __shared__ __attribute__((aligned(16))) unsigned char smem[L * 256];
  unsigned char* Kl = smem;             // [L][32] bf16, swizzled
  unsigned char* Vt = smem + L * 64;    // [32][L] bf16 (V transposed), swizzled
  unsigned char* Pl = smem + L * 128;   // per-wave [16][L] bf16, swizzled

  const int t = threadIdx.x;
  const int wv = t >> 6, lane = t & 63, l15 = lane & 15, l4 = lane >> 4;
  const int h = blockIdx.x & (H_ - 1);
  const int outer = blockIdx.x >> 3;
  const long long base = (long long)outer * obase_mul + h * CA_;
  const long long mb = (long long)outer * mbase_mul;
  const float* biasp = HAS_BIAS ? (bias + (long long)h * (R_ * R_)) : nullptr;

  // stage K: [L][32]
  #pragma unroll
  for(int j = 0; j < L * 4; j += 256){
    int cid = j + t;
    int row = cid >> 2, ko = cid & 3;
    int4 kv = *(const int4*)(kg + base + (long long)row * tstride + ko * 8);
    *(int4*)(Kl + ((row * 64 + ko * 16) ^ ((row & 7) << 4))) = kv;
  }
  // stage V transposed: Vt[c][k]
  if(t < L){
    __attribute__((aligned(16))) u16 tmp[32];
    const u16* vp = vg + base + (long long)t * tstride;
    #pragma unroll
    for(int j2 = 0; j2 < 4; j2++) ((int4*)tmp)[j2] = *(const int4*)(vp + j2 * 8);
    #pragma unroll
    for(int c = 0; c < 32; c++)
      *(u16*)(Vt + (((c * L + t) * 2) ^ ((c & 7) << 4))) = tmp[c];
  }
  __syncthreads();

  unsigned char* Pw = Pl + wv * (L * 32);
  const int NQ = L / 4;                 // queries per wave
  #pragma unroll
  for(int qt = 0; qt < NQ / 16; qt++){
    int qrow0 = wv * NQ + qt * 16;
    bf16x8 aq = *(const bf16x8*)(qg + base + (long long)(qrow0 + l15) * tstride + l4 * 8);
    f32x4 lac[L / 16];
    #pragma unroll
    for(int kt = 0; kt < L / 16; kt++){
      int kr = kt * 16 + l15;
      bf16x8 bk = *(const bf16x8*)(Kl + ((kr * 64 + l4 * 16) ^ ((kr & 7) << 4)));
      f32x4 zz = {0.f, 0.f, 0.f, 0.f};
      lac[kt] = __builtin_amdgcn_mfma_f32_16x16x32_bf16(aq, bk, zz, 0, 0, 0);
    }
    // bias + mask
    #pragma unroll
    for(int kt = 0; kt < L / 16; kt++){
      int key = kt * 16 + l15;
      float mskb = (mask[mb + (long long)key * mstride] - 1.f) * 1e9f;
      #pragma unroll
      for(int r = 0; r < 4; r++){
        float add = mskb;
        if(HAS_BIAS){ int qi = qrow0 + l4 * 4 + r; add += biasp[qi * R_ + key]; }
        lac[kt][r] += add;
      }
    }
    // softmax over key dim (reduce across the 16 lanes sharing a row)
    float mx[4] = {-3e38f, -3e38f, -3e38f, -3e38f};
    #pragma unroll
    for(int kt = 0; kt < L / 16; kt++)
      #pragma unroll
      for(int r = 0; r < 4; r++) mx[r] = fmaxf(mx[r], lac[kt][r]);
    #pragma unroll
    for(int mo = 1; mo < 16; mo <<= 1)
      #pragma unroll
      for(int r = 0; r < 4; r++) mx[r] = fmaxf(mx[r], __shfl_xor(mx[r], mo, 64));
    float sm[4] = {0, 0, 0, 0};
    #pragma unroll
    for(int kt = 0; kt < L / 16; kt++)
      #pragma unroll
      for(int r = 0; r < 4; r++){ float e = __expf(lac[kt][r] - mx[r]); lac[kt][r] = e; sm[r] += e; }
    #pragma unroll
    for(int mo = 1; mo < 16; mo <<= 1)
      #pragma unroll
      for(int r = 0; r < 4; r++) sm[r] += __shfl_xor(sm[r], mo, 64);
    float inv[4];
    #pragma unroll
    for(int r = 0; r < 4; r++) inv[r] = 1.f / sm[r];
    // write normalized P (bf16) to per-wave LDS
    #pragma unroll
    for(int kt = 0; kt < L / 16; kt++){
      int key = kt * 16 + l15;
      #pragma unroll
      for(int r = 0; r < 4; r++){
        int ql = l4 * 4 + r;
        *(u16*)(Pw + (((ql * L + key) * 2) ^ ((ql & 7) << 4))) = f2bf(lac[kt][r] * inv[r]);
      }
    }
    // PV
    f32x4 oac[2] = {{0,0,0,0},{0,0,0,0}};
    #pragma unroll
    for(int ks = 0; ks < L / 32; ks++){
      bf16x8 ap = *(const bf16x8*)(Pw + (((l15 * L + ks * 32 + l4 * 8) * 2) ^ ((l15 & 7) << 4)));
      #pragma unroll
      for(int ct = 0; ct < 2; ct++){
        int c = ct * 16 + l15;
        bf16x8 bv = *(const bf16x8*)(Vt + (((c * L + ks * 32 + l4 * 8) * 2) ^ ((c & 7) << 4)));
        oac[ct] = __builtin_amdgcn_mfma_f32_16x16x32_bf16(ap, bv, oac[ct], 0, 0, 0);
      }
    }
    #pragma unroll
    for(int ct = 0; ct < 2; ct++)
      #pragma unroll
      for(int r = 0; r < 4; r++){
        int qi = qrow0 + l4 * 4 + r, c = ct * 16 + l15;
        og[base + (long long)qi * tstride + c] = f2bf(oac[ct][r]);
      }
  }
}

extern "C" void kernel_launch(void* const* d_in, const int* in_sizes, int n_in,
                              void* d_out, int out_size, void* d_ws, size_t ws_size,
                              hipStream_t stream){
  const float* m        = (const float*)d_in[0];
  const float* m_mask   = (const float*)d_in[1];
  const float* z        = (const float*)d_in[2];
  const float* row_ln_w = (const float*)d_in[3];
  const float* row_ln_b = (const float*)d_in[4];
  const float* row_z_ln_w = (const float*)d_in[5];
  const float* row_z_ln_b = (const float*)d_in[6];
  const float* row_wq   = (const float*)d_in[7];
  const float* row_wk   = (const float*)d_in[8];
  const float* row_wv   = (const float*)d_in[9];
  const float* row_wb   = (const float*)d_in[10];
  const float* row_wg   = (const float*)d_in[11];
  const float* row_bg   = (const float*)d_in[12];
  const float* row_wo   = (const float*)d_in[13];
  const float* row_bo   = (const float*)d_in[14];
  const float* col_ln_w = (const float*)d_in[15];
  const float* col_ln_b = (const float*)d_in[16];
  const float* col_wq   = (const float*)d_in[17];
  const float* col_wk   = (const float*)d_in[18];
  const float* col_wv   = (const float*)d_in[19];
  const float* col_wg   = (const float*)d_in[20];
  const float* col_bg   = (const float*)d_in[21];
  const float* col_wo   = (const float*)d_in[22];
  const float* col_bo   = (const float*)d_in[23];
  const float* tr_ln_w  = (const float*)d_in[24];
  const float* tr_ln_b  = (const float*)d_in[25];
  const float* tr_w1    = (const float*)d_in[26];
  const float* tr_b1    = (const float*)d_in[27];
  const float* tr_w2    = (const float*)d_in[28];
  const float* tr_b2    = (const float*)d_in[29];
  float* out = (float*)d_out;
  char* ws = (char*)d_ws;

  u16* bx  = (u16*)ws;                            // 8388608 elems each
  u16* t_q = bx  + 8388608;
  u16* t_k = t_q + 8388608;
  u16* t_v = t_k + 8388608;
  u16* t_g = t_v + 8388608;
  u16* t_o = t_g + 8388608;
  u16* h1  = t_q;                                 // reused: [32768][1024] spans t_q..t_o
  float* pbias = (float*)(ws + 100663296);        // [8][256][256] fp32
  u16* wt = (u16*)(ws + 102760448);
  u16 *w_rq = wt,          *w_rk = wt + 65536,  *w_rv = wt + 131072,
      *w_rg = wt + 196608, *w_ro = wt + 262144;
  u16 *w_cq = wt + 327680, *w_ck = wt + 393216, *w_cv = wt + 458752,
      *w_cg = wt + 524288, *w_co = wt + 589824;
  u16 *w_1  = wt + 655360, *w_2  = wt + 917504;

  const float qs = 0.17677669529663687f;          // CA^-0.5
  dim3 b256(256);
  // weight transposes (scale folded into wq)
  transpose_w<<<dim3(256),  b256, 0, stream>>>(row_wq, w_rq, 256, 256, qs);
  transpose_w<<<dim3(256),  b256, 0, stream>>>(row_wk, w_rk, 256, 256, 1.f);
  transpose_w<<<dim3(256),  b256, 0, stream>>>(row_wv, w_rv, 256, 256, 1.f);
  transpose_w<<<dim3(256),  b256, 0, stream>>>(row_wg, w_rg, 256, 256, 1.f);
  transpose_w<<<dim3(256),  b256, 0, stream>>>(row_wo, w_ro, 256, 256, 1.f);
  transpose_w<<<dim3(256),  b256, 0, stream>>>(col_wq, w_cq, 256, 256, qs);
  transpose_w<<<dim3(256),  b256, 0, stream>>>(col_wk, w_ck, 256, 256, 1.f);
  transpose_w<<<dim3(256),  b256, 0, stream>>>(col_wv, w_cv, 256, 256, 1.f);
  transpose_w<<<dim3(256),  b256, 0, stream>>>(col_wg, w_cg, 256, 256, 1.f);
  transpose_w<<<dim3(256),  b256, 0, stream>>>(col_wo, w_co, 256, 256, 1.f);
  transpose_w<<<dim3(1024), b256, 0, stream>>>(tr_w1, w_1, 256, 1024, 1.f);
  transpose_w<<<dim3(1024), b256, 0, stream>>>(tr_w2, w_2, 1024, 256, 1.f);

  pair_bias_kernel<<<dim3(16384), b256, 0, stream>>>(z, row_z_ln_w, row_z_ln_b, row_wb, pbias);

  dim3 g256(4, 512), g1024(16, 512);
  // ---- row attention ----
  ln_kernel<<<dim3(8192), b256, 0, stream>>>(m, row_ln_w, row_ln_b, bx);
  gemm_kernel<false,false,false,false,false><<<g256, b256, 0, stream>>>(bx, nullptr, w_rq, nullptr, nullptr, t_q, 32768, 256, 256);
  gemm_kernel<false,false,false,false,false><<<g256, b256, 0, stream>>>(bx, nullptr, w_rk, nullptr, nullptr, t_k, 32768, 256, 256);
  gemm_kernel<false,false,false,false,false><<<g256, b256, 0, stream>>>(bx, nullptr, w_rv, nullptr, nullptr, t_v, 32768, 256, 256);
  gemm_kernel<false,true ,false,false,false><<<g256, b256, 0, stream>>>(bx, nullptr, w_rg, row_bg, nullptr, t_g, 32768, 256, 256);
  atten_kernel<256,true><<<dim3(S_*H_), b256, 0, stream>>>(t_q, t_k, t_v, pbias, m_mask, t_o,
                                                           65536, 256, 256, 1);
  gemm_kernel<true ,false,false,true ,true ><<<g256, b256, 0, stream>>>(t_o, t_g, w_ro, row_bo, m, out, 32768, 256, 256);

  // ---- column attention ----
  ln_kernel<<<dim3(8192), b256, 0, stream>>>(out, col_ln_w, col_ln_b, bx);
  gemm_kernel<false,false,false,false,false><<<g256, b256, 0, stream>>>(bx, nullptr, w_cq, nullptr, nullptr, t_q, 32768, 256, 256);
  gemm_kernel<false,false,false,false,false><<<g256, b256, 0, stream>>>(bx, nullptr, w_ck, nullptr, nullptr, t_k, 32768, 256, 256);
  gemm_kernel<false,false,false,false,false><<<g256, b256, 0, stream>>>(bx, nullptr, w_cv, nullptr, nullptr, t_v, 32768, 256, 256);
  gemm_kernel<false,true ,false,false,false><<<g256, b256, 0, stream>>>(bx, nullptr, w_cg, col_bg, nullptr, t_g, 32768, 256, 256);
  atten_kernel<128,false><<<dim3(R_*H_), b256, 0, stream>>>(t_q, t_k, t_v, nullptr, m_mask, t_o,
                                                            256, 65536, 1, 256);
  gemm_kernel<true ,false,false,true ,true ><<<g256, b256, 0, stream>>>(t_o, t_g, w_co, col_bo, out, out, 32768, 256, 256);

  // ---- transition ----
  ln_kernel<<<dim3(8192), b256, 0, stream>>>(out, tr_ln_w, tr_ln_b, bx);
  gemm_kernel<false,false,true ,false,false><<<g1024, b256, 0, stream>>>(bx, nullptr, w_1, tr_b1, nullptr, h1, 32768, 1024, 256);
  gemm_kernel<false,false,false,true ,true ><<<g256,  b256, 0, stream>>>(h1, nullptr, w_2, tr_b2, out, out, 32768, 256, 1024);
}

// Round 3
// 379.144 us; speedup vs baseline: 1.7500x; 1.7500x over previous
//
#include <hip/hip_runtime.h>
#include <stdint.h>

#define S_ 128
#define R_ 256
#define CM_ 256
#define H_ 8
#define CA_ 32
#define CZ_ 128

typedef unsigned short u16;
typedef __bf16 bf16x8 __attribute__((ext_vector_type(8)));
typedef float f32x4 __attribute__((ext_vector_type(4)));

__device__ __forceinline__ float bf2f(u16 u){ unsigned v = ((unsigned)u) << 16; float f; __builtin_memcpy(&f, &v, 4); return f; }
__device__ __forceinline__ u16 f2bf(float f){ unsigned v; __builtin_memcpy(&v, &f, 4); v += 0x7fffu + ((v >> 16) & 1u); return (u16)(v >> 16); }

__device__ __forceinline__ void gl16(const void* g, void* l){
  __builtin_amdgcn_global_load_lds((const __attribute__((address_space(1))) void*)g,
                                   (__attribute__((address_space(3))) void*)l, 16, 0, 0);
}

// ---------------- all 12 weight transposes in one launch ----------------
struct WSrc { const float* p[12]; };
__global__ __launch_bounds__(256) void transpose_all(WSrc srcs, u16* __restrict__ dst){
  int b = blockIdx.x, t = threadIdx.x;
  int job, idx;
  if(b < 2560){ job = b >> 8; idx = ((b & 255) << 8) + t; }
  else if(b < 3584){ job = 10; idx = ((b - 2560) << 8) + t; }
  else { job = 11; idx = ((b - 3584) << 8) + t; }
  int K = (job == 11) ? 1024 : 256;
  int N = (job == 10) ? 1024 : 256;
  int off;
  if(job < 10) off = job * 65536;
  else if(job == 10) off = 655360;
  else off = 917504;
  int k = idx / N, n = idx - k * N;
  float sc = (job == 0 || job == 5) ? 0.17677669529663687f : 1.f;
  dst[off + n * K + k] = f2bf(srcs.p[job][idx] * sc);
}

// ---------------- LayerNorm over last dim 256, fp32 in -> bf16 out ----------------
__global__ __launch_bounds__(256) void ln_kernel(const float* __restrict__ in, const float* __restrict__ w,
                          const float* __restrict__ b, u16* __restrict__ out){
  int wv = threadIdx.x >> 6, lane = threadIdx.x & 63;
  long long row = (long long)blockIdx.x * 4 + wv;
  const float* rp = in + row * CM_;
  float v[4]; float s = 0.f;
  #pragma unroll
  for(int i = 0; i < 4; i++){ v[i] = rp[lane + i * 64]; s += v[i]; }
  for(int mo = 32; mo; mo >>= 1) s += __shfl_xor(s, mo, 64);
  float mu = s * (1.f / CM_);
  float s2 = 0.f;
  #pragma unroll
  for(int i = 0; i < 4; i++){ float d = v[i] - mu; s2 += d * d; }
  for(int mo = 32; mo; mo >>= 1) s2 += __shfl_xor(s2, mo, 64);
  float rstd = rsqrtf(s2 * (1.f / CM_) + 1e-5f);
  u16* op = out + row * CM_;
  #pragma unroll
  for(int i = 0; i < 4; i++){
    int c = lane + i * 64;
    op[c] = f2bf((v[i] - mu) * rstd * w[c] + b[c]);
  }
}

// ---------------- pair bias: LN(z) @ wb -> permuted bf16 [h][qt][kt][lane][r] ----------------
__global__ __launch_bounds__(256) void pair_bias_kernel(const float* __restrict__ z, const float* __restrict__ lnw,
                                 const float* __restrict__ lnb, const float* __restrict__ wb,
                                 u16* __restrict__ pb){
  int wv = threadIdx.x >> 6, lane = threadIdx.x & 63;
  long long row = (long long)blockIdx.x * 4 + wv;        // q*256 + k
  const float* rp = z + row * CZ_;
  float v0 = rp[lane], v1 = rp[lane + 64];
  float s = v0 + v1;
  for(int mo = 32; mo; mo >>= 1) s += __shfl_xor(s, mo, 64);
  float mu = s * (1.f / CZ_);
  float d0 = v0 - mu, d1 = v1 - mu;
  float s2 = d0 * d0 + d1 * d1;
  for(int mo = 32; mo; mo >>= 1) s2 += __shfl_xor(s2, mo, 64);
  float rstd = rsqrtf(s2 * (1.f / CZ_) + 1e-5f);
  float x0 = d0 * rstd * lnw[lane] + lnb[lane];
  float x1 = d1 * rstd * lnw[lane + 64] + lnb[lane + 64];
  float acc[8];
  #pragma unroll
  for(int h = 0; h < 8; h++)
    acc[h] = x0 * wb[lane * 8 + h] + x1 * wb[(lane + 64) * 8 + h];
  for(int mo = 32; mo; mo >>= 1){
    #pragma unroll
    for(int h = 0; h < 8; h++) acc[h] += __shfl_xor(acc[h], mo, 64);
  }
  if(lane < 8){
    int q = (int)(row >> 8), k = (int)(row & 255);
    int off = (((lane * 16 + (q >> 4)) * 16 + (k >> 4)) << 10)
            + ((((q >> 2) & 3) * 16 + (k & 15)) << 2) + (q & 3);
    pb[off] = f2bf(acc[lane]);
  }
}

// ---------------- MFMA GEMM 128x128 tile, BK=64, global_load_lds + XOR swizzle ----------------
template<bool HAS_BIAS, bool HAS_SIG, bool RELU, bool RES, bool F32OUT>
__global__ __launch_bounds__(256) void gemm128(
    const u16* __restrict__ A, const u16* __restrict__ Wt,
    const float* __restrict__ bias, const float* __restrict__ res,
    void* __restrict__ outv, int M, int N, int K, int sigStart){
  __shared__ __attribute__((aligned(16))) unsigned char Ab[16384];
  __shared__ __attribute__((aligned(16))) unsigned char Bb[16384];
  const int t = threadIdx.x;
  const int wv = t >> 6, lane = t & 63, l15 = lane & 15, l4 = lane >> 4;
  const int wm = wv >> 1, wn = wv & 1;
  const long long m0 = (long long)blockIdx.y * 128;
  const int n0 = blockIdx.x * 128;
  const int srow = t >> 3;                         // 0..31
  const int ksw  = ((t & 7) ^ (srow & 7)) * 8;     // pre-swizzled k offset (elems)
  const u16* Ag = A  + (m0 + srow) * (long long)K + ksw;
  const u16* Bg = Wt + (long long)(n0 + srow) * K + ksw;
  f32x4 acc[4][4] = {};
  for(int kk = 0; kk < K; kk += 64){
    #pragma unroll
    for(int i = 0; i < 4; i++){
      gl16(Ag + (long long)i * 32 * K + kk, Ab + wv * 1024 + lane * 16 + i * 4096);
      gl16(Bg + (long long)i * 32 * K + kk, Bb + wv * 1024 + lane * 16 + i * 4096);
    }
    asm volatile("s_waitcnt vmcnt(0)" ::: "memory");
    __syncthreads();
    #pragma unroll
    for(int kh = 0; kh < 2; kh++){
      bf16x8 af[4], bq[4];
      #pragma unroll
      for(int mt = 0; mt < 4; mt++){
        int rr = wm * 64 + mt * 16 + l15;
        af[mt] = *(const bf16x8*)(Ab + rr * 128 + ((kh * 64 + l4 * 16) ^ ((rr & 7) << 4)));
      }
      #pragma unroll
      for(int nt = 0; nt < 4; nt++){
        int rr = wn * 64 + nt * 16 + l15;
        bq[nt] = *(const bf16x8*)(Bb + rr * 128 + ((kh * 64 + l4 * 16) ^ ((rr & 7) << 4)));
      }
      #pragma unroll
      for(int mt = 0; mt < 4; mt++)
        #pragma unroll
        for(int nt = 0; nt < 4; nt++)
          acc[mt][nt] = __builtin_amdgcn_mfma_f32_16x16x32_bf16(af[mt], bq[nt], acc[mt][nt], 0, 0, 0);
    }
    __syncthreads();
  }
  #pragma unroll
  for(int nt = 0; nt < 4; nt++){
    int ncol = n0 + wn * 64 + nt * 16 + l15;
    float bnt = 0.f;
    if(HAS_BIAS){
      if(HAS_SIG) bnt = (ncol >= sigStart) ? bias[ncol - sigStart] : 0.f;
      else        bnt = bias[ncol];
    }
    #pragma unroll
    for(int mt = 0; mt < 4; mt++){
      #pragma unroll
      for(int r = 0; r < 4; r++){
        long long mrow = m0 + wm * 64 + mt * 16 + l4 * 4 + r;
        float v = acc[mt][nt][r] + bnt;
        if(HAS_SIG){ if(ncol >= sigStart) v = 1.f / (1.f + __expf(-v)); }
        if(RELU) v = v > 0.f ? v : 0.f;
        if(RES)  v += res[mrow * N + ncol];
        if(F32OUT) ((float*)outv)[mrow * N + ncol] = v;
        else       ((u16*)outv)[mrow * N + ncol] = f2bf(v);
      }
    }
  }
}

// ---------------- fused attention, chunked-P, gated epilogue ----------------
template<int L, bool HAS_BIAS>
__global__ __launch_bounds__(256) void atten_kernel(
    const u16* __restrict__ qg, const u16* __restrict__ kg, const u16* __restrict__ vg,
    const u16* __restrict__ gg, const u16* __restrict__ pb, const float* __restrict__ mask,
    u16* __restrict__ og,
    long long obase_mul, long long tstride, long long obase_o, long long ostride,
    long long mbase_mul, int mstride){
  __shared__ __attribute__((aligned(16))) unsigned char smem[L * 128 + 8192];
  unsigned char* Kl = smem;              // [L][32] bf16, full-addr XOR swizzle
  unsigned char* Vt = smem + L * 64;     // [32][L] bf16 (V^T), swizzled
  unsigned char* Pl = smem + L * 128;    // per-wave [16][64] bf16 chunk

  const int t = threadIdx.x;
  const int wv = t >> 6, lane = t & 63, l15 = lane & 15, l4 = lane >> 4;
  const int h = blockIdx.x & 7;
  const int outer = blockIdx.x >> 3;
  const long long base  = (long long)outer * obase_mul + h * CA_;
  const long long baseo = (long long)outer * obase_o  + h * CA_;
  const long long mb = (long long)outer * mbase_mul;

  #pragma unroll
  for(int j = 0; j < L * 4; j += 256){
    int cid = j + t;
    int row = cid >> 2, ko = cid & 3;
    int4 kv = *(const int4*)(kg + base + (long long)row * tstride + ko * 8);
    *(int4*)(Kl + ((row * 64 + ko * 16) ^ ((row & 7) << 4))) = kv;
  }
  if(t < L){
    __attribute__((aligned(16))) u16 tmp[32];
    const u16* vp = vg + base + (long long)t * tstride;
    #pragma unroll
    for(int j2 = 0; j2 < 4; j2++) ((int4*)tmp)[j2] = *(const int4*)(vp + j2 * 8);
    #pragma unroll
    for(int c = 0; c < 32; c++)
      *(u16*)(Vt + (((c * L + t) * 2) ^ ((c & 7) << 4))) = tmp[c];
  }
  __syncthreads();

  float mskb[L / 16];
  #pragma unroll
  for(int kt = 0; kt < L / 16; kt++)
    mskb[kt] = (mask[mb + (long long)(kt * 16 + l15) * mstride] - 1.f) * 1e9f;

  unsigned char* Pw = Pl + wv * 2048;
  const int NQ = L / 4;
  #pragma unroll
  for(int qt = 0; qt < NQ / 16; qt++){
    const int qrow0 = wv * NQ + qt * 16;
    bf16x8 aq = *(const bf16x8*)(qg + base + (long long)(qrow0 + l15) * tstride + l4 * 8);
    f32x4 lac[L / 16];
    #pragma unroll
    for(int kt = 0; kt < L / 16; kt++){
      int kr = kt * 16 + l15;
      bf16x8 bk = *(const bf16x8*)(Kl + ((kr * 64 + l4 * 16) ^ ((kr & 7) << 4)));
      f32x4 zz = {0.f, 0.f, 0.f, 0.f};
      lac[kt] = __builtin_amdgcn_mfma_f32_16x16x32_bf16(aq, bk, zz, 0, 0, 0);
    }
    if(HAS_BIAS){
      const u16* tile = pb + (((h * 16 + (qrow0 >> 4)) * 16) << 10) + lane * 4;
      #pragma unroll
      for(int kt = 0; kt < L / 16; kt++){
        ushort4 b4 = *(const ushort4*)(tile + (kt << 10));
        lac[kt][0] += bf2f(b4.x); lac[kt][1] += bf2f(b4.y);
        lac[kt][2] += bf2f(b4.z); lac[kt][3] += bf2f(b4.w);
      }
    }
    #pragma unroll
    for(int kt = 0; kt < L / 16; kt++){
      float mm = mskb[kt];
      #pragma unroll
      for(int r = 0; r < 4; r++) lac[kt][r] += mm;
    }
    // softmax over keys (reduce across 16 lanes l15)
    float mx[4] = {-3e38f, -3e38f, -3e38f, -3e38f};
    #pragma unroll
    for(int kt = 0; kt < L / 16; kt++)
      #pragma unroll
      for(int r = 0; r < 4; r++) mx[r] = fmaxf(mx[r], lac[kt][r]);
    #pragma unroll
    for(int mo = 1; mo < 16; mo <<= 1)
      #pragma unroll
      for(int r = 0; r < 4; r++) mx[r] = fmaxf(mx[r], __shfl_xor(mx[r], mo, 64));
    float sm[4] = {0, 0, 0, 0};
    #pragma unroll
    for(int kt = 0; kt < L / 16; kt++)
      #pragma unroll
      for(int r = 0; r < 4; r++){ float e = __expf(lac[kt][r] - mx[r]); lac[kt][r] = e; sm[r] += e; }
    #pragma unroll
    for(int mo = 1; mo < 16; mo <<= 1)
      #pragma unroll
      for(int r = 0; r < 4; r++) sm[r] += __shfl_xor(sm[r], mo, 64);
    float inv[4];
    #pragma unroll
    for(int r = 0; r < 4; r++) inv[r] = 1.f / sm[r];
    // chunked PV: write normalized P [16][64], consume immediately
    f32x4 oac[2] = {{0,0,0,0},{0,0,0,0}};
    #pragma unroll
    for(int ch = 0; ch < L / 64; ch++){
      #pragma unroll
      for(int i = 0; i < 4; i++){
        #pragma unroll
        for(int r = 0; r < 4; r++){
          int qp = l4 * 4 + r;
          *(u16*)(Pw + qp * 128 + ((((i * 16 + l15) * 2)) ^ ((qp & 7) << 4))) =
              f2bf(lac[ch * 4 + i][r] * inv[r]);
        }
      }
      #pragma unroll
      for(int ksl = 0; ksl < 2; ksl++){
        bf16x8 ap = *(const bf16x8*)(Pw + l15 * 128 + ((ksl * 64 + l4 * 16) ^ ((l15 & 7) << 4)));
        #pragma unroll
        for(int ct = 0; ct < 2; ct++){
          int c = ct * 16 + l15;
          bf16x8 bv = *(const bf16x8*)(Vt + (((c * L + ch * 64 + ksl * 32 + l4 * 8) * 2) ^ ((c & 7) << 4)));
          oac[ct] = __builtin_amdgcn_mfma_f32_16x16x32_bf16(ap, bv, oac[ct], 0, 0, 0);
        }
      }
    }
    // epilogue: multiply sigmoid-gate, store
    #pragma unroll
    for(int ct = 0; ct < 2; ct++)
      #pragma unroll
      for(int r = 0; r < 4; r++){
        int qi = qrow0 + l4 * 4 + r, c = ct * 16 + l15;
        float g = bf2f(gg[base + (long long)qi * tstride + c]);
        og[baseo + (long long)qi * ostride + c] = f2bf(oac[ct][r] * g);
      }
  }
}

extern "C" void kernel_launch(void* const* d_in, const int* in_sizes, int n_in,
                              void* d_out, int out_size, void* d_ws, size_t ws_size,
                              hipStream_t stream){
  const float* m        = (const float*)d_in[0];
  const float* m_mask   = (const float*)d_in[1];
  const float* z        = (const float*)d_in[2];
  const float* row_ln_w = (const float*)d_in[3];
  const float* row_ln_b = (const float*)d_in[4];
  const float* row_z_ln_w = (const float*)d_in[5];
  const float* row_z_ln_b = (const float*)d_in[6];
  const float* row_bg   = (const float*)d_in[12];
  const float* row_bo   = (const float*)d_in[14];
  const float* col_ln_w = (const float*)d_in[15];
  const float* col_ln_b = (const float*)d_in[16];
  const float* col_bg   = (const float*)d_in[21];
  const float* col_bo   = (const float*)d_in[23];
  const float* tr_ln_w  = (const float*)d_in[24];
  const float* tr_ln_b  = (const float*)d_in[25];
  const float* tr_b1    = (const float*)d_in[27];
  const float* tr_b2    = (const float*)d_in[29];
  float* out = (float*)d_out;
  char* ws = (char*)d_ws;

  u16* bx  = (u16*)ws;                    // [32768][256] bf16
  u16* fq  = bx + 8388608;                // [32768][1024] bf16 (QKVG fused / h1)
  u16* t_o = fq + 33554432;               // [32768][256] bf16
  u16* pb  = t_o + 8388608;               // permuted pair bias, 2M bf16
  u16* wt  = pb + 2097152;                // transposed weights

  WSrc srcs;
  srcs.p[0] = (const float*)d_in[7];   // row_wq
  srcs.p[1] = (const float*)d_in[8];   // row_wk
  srcs.p[2] = (const float*)d_in[9];   // row_wv
  srcs.p[3] = (const float*)d_in[11];  // row_wg
  srcs.p[4] = (const float*)d_in[13];  // row_wo
  srcs.p[5] = (const float*)d_in[17];  // col_wq
  srcs.p[6] = (const float*)d_in[18];  // col_wk
  srcs.p[7] = (const float*)d_in[19];  // col_wv
  srcs.p[8] = (const float*)d_in[20];  // col_wg
  srcs.p[9] = (const float*)d_in[22];  // col_wo
  srcs.p[10] = (const float*)d_in[26]; // tr_w1
  srcs.p[11] = (const float*)d_in[28]; // tr_w2

  dim3 b256(256);
  transpose_all<<<dim3(4608), b256, 0, stream>>>(srcs, wt);
  pair_bias_kernel<<<dim3(16384), b256, 0, stream>>>(z, row_z_ln_w, row_z_ln_b,
                                                     (const float*)d_in[10], pb);

  // ---- row attention ----
  ln_kernel<<<dim3(8192), b256, 0, stream>>>(m, row_ln_w, row_ln_b, bx);
  gemm128<true,true,false,false,false><<<dim3(8,256), b256, 0, stream>>>(
      bx, wt, row_bg, nullptr, fq, 32768, 1024, 256, 768);
  atten_kernel<256,true><<<dim3(1024), b256, 0, stream>>>(
      fq, fq + 256, fq + 512, fq + 768, pb, m_mask, t_o,
      262144, 1024, 65536, 256, 256, 1);
  gemm128<true,false,false,true,true><<<dim3(2,256), b256, 0, stream>>>(
      t_o, wt + 262144, row_bo, m, out, 32768, 256, 256, 0);

  // ---- column attention ----
  ln_kernel<<<dim3(8192), b256, 0, stream>>>(out, col_ln_w, col_ln_b, bx);
  gemm128<true,true,false,false,false><<<dim3(8,256), b256, 0, stream>>>(
      bx, wt + 327680, col_bg, nullptr, fq, 32768, 1024, 256, 768);
  atten_kernel<128,false><<<dim3(2048), b256, 0, stream>>>(
      fq, fq + 256, fq + 512, fq + 768, nullptr, m_mask, t_o,
      1024, 262144, 256, 65536, 1, 256);
  gemm128<true,false,false,true,true><<<dim3(2,256), b256, 0, stream>>>(
      t_o, wt + 589824, col_bo, out, out, 32768, 256, 256, 0);

  // ---- transition ----
  ln_kernel<<<dim3(8192), b256, 0, stream>>>(out, tr_ln_w, tr_ln_b, bx);
  gemm128<true,false,true,false,false><<<dim3(8,256), b256, 0, stream>>>(
      bx, wt + 655360, tr_b1, nullptr, fq, 32768, 1024, 256, 0);
  gemm128<true,false,false,true,true><<<dim3(2,256), b256, 0, stream>>>(
      fq, wt + 917504, tr_b2, out, out, 32768, 256, 1024, 0);
}

// Round 4
// 338.809 us; speedup vs baseline: 1.9584x; 1.1190x over previous
//
#include <hip/hip_runtime.h>
#include <stdint.h>

#define S_ 128
#define R_ 256
#define CM_ 256
#define H_ 8
#define CA_ 32
#define CZ_ 128

typedef unsigned short u16;
typedef __bf16 bf16x8 __attribute__((ext_vector_type(8)));
typedef float f32x4 __attribute__((ext_vector_type(4)));

__device__ __forceinline__ float bf2f(u16 u){ unsigned v = ((unsigned)u) << 16; float f; __builtin_memcpy(&f, &v, 4); return f; }
__device__ __forceinline__ u16 f2bf(float f){ __bf16 h = (__bf16)f; u16 u; __builtin_memcpy(&u, &h, 2); return u; }

__device__ __forceinline__ void gl16(const void* g, void* l){
  __builtin_amdgcn_global_load_lds((const __attribute__((address_space(1))) void*)g,
                                   (__attribute__((address_space(3))) void*)l, 16, 0, 0);
}

// ---------------- all 12 weight transposes in one launch ----------------
struct WSrc { const float* p[12]; };
__global__ __launch_bounds__(256) void transpose_all(WSrc srcs, u16* __restrict__ dst){
  int b = blockIdx.x, t = threadIdx.x;
  int job, idx;
  if(b < 2560){ job = b >> 8; idx = ((b & 255) << 8) + t; }
  else if(b < 3584){ job = 10; idx = ((b - 2560) << 8) + t; }
  else { job = 11; idx = ((b - 3584) << 8) + t; }
  int K = (job == 11) ? 1024 : 256;
  int N = (job == 10) ? 1024 : 256;
  int off;
  if(job < 10) off = job * 65536;
  else if(job == 10) off = 655360;
  else off = 917504;
  int k = idx / N, n = idx - k * N;
  float sc = (job == 0 || job == 5) ? 0.17677669529663687f : 1.f;
  dst[off + n * K + k] = f2bf(srcs.p[job][idx] * sc);
}

// ---------------- LayerNorm over last dim 256, fp32 in -> bf16 out ----------------
__global__ __launch_bounds__(256) void ln_kernel(const float* __restrict__ in, const float* __restrict__ w,
                          const float* __restrict__ b, u16* __restrict__ out){
  int wv = threadIdx.x >> 6, lane = threadIdx.x & 63;
  long long row = (long long)blockIdx.x * 4 + wv;
  float4 v = ((const float4*)(in + row * CM_))[lane];
  float s = v.x + v.y + v.z + v.w;
  for(int mo = 32; mo; mo >>= 1) s += __shfl_xor(s, mo, 64);
  float mu = s * (1.f / CM_);
  float dx = v.x - mu, dy = v.y - mu, dz = v.z - mu, dw = v.w - mu;
  float s2 = dx * dx + dy * dy + dz * dz + dw * dw;
  for(int mo = 32; mo; mo >>= 1) s2 += __shfl_xor(s2, mo, 64);
  float rstd = rsqrtf(s2 * (1.f / CM_) + 1e-5f);
  float4 w4 = ((const float4*)w)[lane];
  float4 b4 = ((const float4*)b)[lane];
  ushort4 st;
  st.x = f2bf(dx * rstd * w4.x + b4.x);
  st.y = f2bf(dy * rstd * w4.y + b4.y);
  st.z = f2bf(dz * rstd * w4.z + b4.z);
  st.w = f2bf(dw * rstd * w4.w + b4.w);
  *(ushort4*)(out + row * CM_ + lane * 4) = st;
}

// ---------------- pair bias: LN(z) @ wb -> permuted bf16 [h][qt][kt][lane][r] ----------------
__global__ __launch_bounds__(256) void pair_bias_kernel(const float* __restrict__ z, const float* __restrict__ lnw,
                                 const float* __restrict__ lnb, const float* __restrict__ wb,
                                 u16* __restrict__ pb){
  int wv = threadIdx.x >> 6, lane = threadIdx.x & 63;
  long long row = (long long)blockIdx.x * 4 + wv;        // q*256 + k
  float2 v = ((const float2*)(z + row * CZ_))[lane];
  float s = v.x + v.y;
  for(int mo = 32; mo; mo >>= 1) s += __shfl_xor(s, mo, 64);
  float mu = s * (1.f / CZ_);
  float d0 = v.x - mu, d1 = v.y - mu;
  float s2 = d0 * d0 + d1 * d1;
  for(int mo = 32; mo; mo >>= 1) s2 += __shfl_xor(s2, mo, 64);
  float rstd = rsqrtf(s2 * (1.f / CZ_) + 1e-5f);
  float2 lw = ((const float2*)lnw)[lane], lb = ((const float2*)lnb)[lane];
  float x0 = d0 * rstd * lw.x + lb.x;
  float x1 = d1 * rstd * lw.y + lb.y;
  const float4* wp = (const float4*)(wb + lane * 16);
  float4 w0a = wp[0], w0b = wp[1], w1a = wp[2], w1b = wp[3];
  float acc[8];
  acc[0] = x0 * w0a.x + x1 * w1a.x; acc[1] = x0 * w0a.y + x1 * w1a.y;
  acc[2] = x0 * w0a.z + x1 * w1a.z; acc[3] = x0 * w0a.w + x1 * w1a.w;
  acc[4] = x0 * w0b.x + x1 * w1b.x; acc[5] = x0 * w0b.y + x1 * w1b.y;
  acc[6] = x0 * w0b.z + x1 * w1b.z; acc[7] = x0 * w0b.w + x1 * w1b.w;
  for(int mo = 32; mo; mo >>= 1){
    #pragma unroll
    for(int h = 0; h < 8; h++) acc[h] += __shfl_xor(acc[h], mo, 64);
  }
  if(lane < 8){
    int q = (int)(row >> 8), k = (int)(row & 255);
    int off = (((lane * 16 + (q >> 4)) * 16 + (k >> 4)) << 10)
            + ((((q >> 2) & 3) * 16 + (k & 15)) << 2) + (q & 3);
    pb[off] = f2bf(acc[lane]);
  }
}

// ---------------- MFMA GEMM 128x128 tile, BK=64, global_load_lds + XOR swizzle ----------------
// XCD-aware remap: each XCD owns a contiguous M-strip (A-panel stays in its L2).
template<bool HAS_BIAS, bool HAS_SIG, bool RELU, bool RES, bool F32OUT>
__global__ __launch_bounds__(256) void gemm128(
    const u16* __restrict__ A, const u16* __restrict__ Wt,
    const float* __restrict__ bias, const float* __restrict__ res,
    void* __restrict__ outv, int M, int N, int K, int sigStart){
  __shared__ __attribute__((aligned(16))) unsigned char Ab[16384];
  __shared__ __attribute__((aligned(16))) unsigned char Bb[16384];
  const int t = threadIdx.x;
  const int wv = t >> 6, lane = t & 63, l15 = lane & 15, l4 = lane >> 4;
  const int wm = wv >> 1, wn = wv & 1;
  // bijective XCD remap (MB = gridDim.y divisible by 8)
  const unsigned flat = blockIdx.y * gridDim.x + blockIdx.x;
  const unsigned NB = gridDim.x, mper = gridDim.y >> 3;
  const unsigned xcd = flat & 7, j = flat >> 3;
  const unsigned n_blk = j % NB, m_blk = xcd * mper + j / NB;
  const long long m0 = (long long)m_blk * 128;
  const int n0 = n_blk * 128;
  const int srow = t >> 3;                         // 0..31
  const int ksw  = ((t & 7) ^ (srow & 7)) * 8;     // pre-swizzled k offset (elems)
  const u16* Ag = A  + (m0 + srow) * (long long)K + ksw;
  const u16* Bg = Wt + (long long)(n0 + srow) * K + ksw;
  f32x4 acc[4][4] = {};
  for(int kk = 0; kk < K; kk += 64){
    #pragma unroll
    for(int i = 0; i < 4; i++){
      gl16(Ag + (long long)i * 32 * K + kk, Ab + wv * 1024 + lane * 16 + i * 4096);
      gl16(Bg + (long long)i * 32 * K + kk, Bb + wv * 1024 + lane * 16 + i * 4096);
    }
    asm volatile("s_waitcnt vmcnt(0)" ::: "memory");
    __syncthreads();
    #pragma unroll
    for(int kh = 0; kh < 2; kh++){
      bf16x8 af[4], bq[4];
      #pragma unroll
      for(int mt = 0; mt < 4; mt++){
        int rr = wm * 64 + mt * 16 + l15;
        af[mt] = *(const bf16x8*)(Ab + rr * 128 + ((kh * 64 + l4 * 16) ^ ((rr & 7) << 4)));
      }
      #pragma unroll
      for(int nt = 0; nt < 4; nt++){
        int rr = wn * 64 + nt * 16 + l15;
        bq[nt] = *(const bf16x8*)(Bb + rr * 128 + ((kh * 64 + l4 * 16) ^ ((rr & 7) << 4)));
      }
      #pragma unroll
      for(int mt = 0; mt < 4; mt++)
        #pragma unroll
        for(int nt = 0; nt < 4; nt++)
          acc[mt][nt] = __builtin_amdgcn_mfma_f32_16x16x32_bf16(af[mt], bq[nt], acc[mt][nt], 0, 0, 0);
    }
    __syncthreads();
  }
  #pragma unroll
  for(int nt = 0; nt < 4; nt++){
    int ncol = n0 + wn * 64 + nt * 16 + l15;
    float bnt = 0.f;
    if(HAS_BIAS){
      if(HAS_SIG) bnt = (ncol >= sigStart) ? bias[ncol - sigStart] : 0.f;
      else        bnt = bias[ncol];
    }
    #pragma unroll
    for(int mt = 0; mt < 4; mt++){
      #pragma unroll
      for(int r = 0; r < 4; r++){
        long long mrow = m0 + wm * 64 + mt * 16 + l4 * 4 + r;
        float v = acc[mt][nt][r] + bnt;
        if(HAS_SIG){ if(ncol >= sigStart) v = 1.f / (1.f + __expf(-v)); }
        if(RELU) v = v > 0.f ? v : 0.f;
        if(RES)  v += res[mrow * N + ncol];
        if(F32OUT) ((float*)outv)[mrow * N + ncol] = v;
        else       ((u16*)outv)[mrow * N + ncol] = f2bf(v);
      }
    }
  }
}

// ---------------- fused attention, chunked-P, gated epilogue ----------------
template<int L, bool HAS_BIAS>
__global__ __launch_bounds__(256) void atten_kernel(
    const u16* __restrict__ qg, const u16* __restrict__ kg, const u16* __restrict__ vg,
    const u16* __restrict__ gg, const u16* __restrict__ pb, const float* __restrict__ mask,
    u16* __restrict__ og,
    long long obase_mul, long long tstride, long long obase_o, long long ostride,
    long long mbase_mul, int mstride){
  __shared__ __attribute__((aligned(16))) unsigned char smem[L * 128 + 8192];
  unsigned char* Kl = smem;              // [L][32] bf16, full-addr XOR swizzle
  unsigned char* Vt = smem + L * 64;     // [32][L] bf16 (V^T), swizzled
  unsigned char* Pl = smem + L * 128;    // per-wave [16][64] bf16 chunk

  const int t = threadIdx.x;
  const int wv = t >> 6, lane = t & 63, l15 = lane & 15, l4 = lane >> 4;
  const int h = blockIdx.x & 7;
  const int outer = blockIdx.x >> 3;
  const long long base  = (long long)outer * obase_mul + h * CA_;
  const long long baseo = (long long)outer * obase_o  + h * CA_;
  const long long mb = (long long)outer * mbase_mul;

  #pragma unroll
  for(int j = 0; j < L * 4; j += 256){
    int cid = j + t;
    int row = cid >> 2, ko = cid & 3;
    int4 kv = *(const int4*)(kg + base + (long long)row * tstride + ko * 8);
    *(int4*)(Kl + ((row * 64 + ko * 16) ^ ((row & 7) << 4))) = kv;
  }
  if(t < L){
    __attribute__((aligned(16))) u16 tmp[32];
    const u16* vp = vg + base + (long long)t * tstride;
    #pragma unroll
    for(int j2 = 0; j2 < 4; j2++) ((int4*)tmp)[j2] = *(const int4*)(vp + j2 * 8);
    #pragma unroll
    for(int c = 0; c < 32; c++)
      *(u16*)(Vt + (((c * L + t) * 2) ^ ((c & 7) << 4))) = tmp[c];
  }
  __syncthreads();

  float mskb[L / 16];
  #pragma unroll
  for(int kt = 0; kt < L / 16; kt++)
    mskb[kt] = (mask[mb + (long long)(kt * 16 + l15) * mstride] - 1.f) * 1e9f;

  unsigned char* Pw = Pl + wv * 2048;
  const int NQ = L / 4;
  #pragma unroll
  for(int qt = 0; qt < NQ / 16; qt++){
    const int qrow0 = wv * NQ + qt * 16;
    bf16x8 aq = *(const bf16x8*)(qg + base + (long long)(qrow0 + l15) * tstride + l4 * 8);
    f32x4 lac[L / 16];
    #pragma unroll
    for(int kt = 0; kt < L / 16; kt++){
      int kr = kt * 16 + l15;
      bf16x8 bk = *(const bf16x8*)(Kl + ((kr * 64 + l4 * 16) ^ ((kr & 7) << 4)));
      f32x4 zz = {0.f, 0.f, 0.f, 0.f};
      lac[kt] = __builtin_amdgcn_mfma_f32_16x16x32_bf16(aq, bk, zz, 0, 0, 0);
    }
    // bias + mask in one pass
    #pragma unroll
    for(int kt = 0; kt < L / 16; kt++){
      float mm = mskb[kt];
      if(HAS_BIAS){
        const u16* tile = pb + (((h * 16 + (qrow0 >> 4)) * 16) << 10) + lane * 4;
        ushort4 b4 = *(const ushort4*)(tile + (kt << 10));
        lac[kt][0] += mm + bf2f(b4.x); lac[kt][1] += mm + bf2f(b4.y);
        lac[kt][2] += mm + bf2f(b4.z); lac[kt][3] += mm + bf2f(b4.w);
      } else {
        #pragma unroll
        for(int r = 0; r < 4; r++) lac[kt][r] += mm;
      }
    }
    // softmax over keys (reduce across 16 lanes l15)
    float mx[4] = {-3e38f, -3e38f, -3e38f, -3e38f};
    #pragma unroll
    for(int kt = 0; kt < L / 16; kt++)
      #pragma unroll
      for(int r = 0; r < 4; r++) mx[r] = fmaxf(mx[r], lac[kt][r]);
    #pragma unroll
    for(int mo = 1; mo < 16; mo <<= 1)
      #pragma unroll
      for(int r = 0; r < 4; r++) mx[r] = fmaxf(mx[r], __shfl_xor(mx[r], mo, 64));
    float sm[4] = {0, 0, 0, 0};
    #pragma unroll
    for(int kt = 0; kt < L / 16; kt++)
      #pragma unroll
      for(int r = 0; r < 4; r++){ float e = __expf(lac[kt][r] - mx[r]); lac[kt][r] = e; sm[r] += e; }
    #pragma unroll
    for(int mo = 1; mo < 16; mo <<= 1)
      #pragma unroll
      for(int r = 0; r < 4; r++) sm[r] += __shfl_xor(sm[r], mo, 64);
    float inv[4];
    #pragma unroll
    for(int r = 0; r < 4; r++) inv[r] = 1.f / sm[r];
    // chunked PV on UNNORMALIZED P (inv folded into epilogue)
    f32x4 oac[2] = {{0,0,0,0},{0,0,0,0}};
    #pragma unroll
    for(int ch = 0; ch < L / 64; ch++){
      #pragma unroll
      for(int i = 0; i < 4; i++){
        #pragma unroll
        for(int r = 0; r < 4; r++){
          int qp = l4 * 4 + r;
          *(u16*)(Pw + qp * 128 + ((((i * 16 + l15) * 2)) ^ ((qp & 7) << 4))) =
              f2bf(lac[ch * 4 + i][r]);
        }
      }
      #pragma unroll
      for(int ksl = 0; ksl < 2; ksl++){
        bf16x8 ap = *(const bf16x8*)(Pw + l15 * 128 + ((ksl * 64 + l4 * 16) ^ ((l15 & 7) << 4)));
        #pragma unroll
        for(int ct = 0; ct < 2; ct++){
          int c = ct * 16 + l15;
          bf16x8 bv = *(const bf16x8*)(Vt + (((c * L + ch * 64 + ksl * 32 + l4 * 8) * 2) ^ ((c & 7) << 4)));
          oac[ct] = __builtin_amdgcn_mfma_f32_16x16x32_bf16(ap, bv, oac[ct], 0, 0, 0);
        }
      }
    }
    // epilogue: normalize, multiply sigmoid-gate, store
    #pragma unroll
    for(int ct = 0; ct < 2; ct++)
      #pragma unroll
      for(int r = 0; r < 4; r++){
        int qi = qrow0 + l4 * 4 + r, c = ct * 16 + l15;
        float g = bf2f(gg[base + (long long)qi * tstride + c]);
        og[baseo + (long long)qi * ostride + c] = f2bf(oac[ct][r] * inv[r] * g);
      }
  }
}

extern "C" void kernel_launch(void* const* d_in, const int* in_sizes, int n_in,
                              void* d_out, int out_size, void* d_ws, size_t ws_size,
                              hipStream_t stream){
  const float* m        = (const float*)d_in[0];
  const float* m_mask   = (const float*)d_in[1];
  const float* z        = (const float*)d_in[2];
  const float* row_ln_w = (const float*)d_in[3];
  const float* row_ln_b = (const float*)d_in[4];
  const float* row_z_ln_w = (const float*)d_in[5];
  const float* row_z_ln_b = (const float*)d_in[6];
  const float* row_bg   = (const float*)d_in[12];
  const float* row_bo   = (const float*)d_in[14];
  const float* col_ln_w = (const float*)d_in[15];
  const float* col_ln_b = (const float*)d_in[16];
  const float* col_bg   = (const float*)d_in[21];
  const float* col_bo   = (const float*)d_in[23];
  const float* tr_ln_w  = (const float*)d_in[24];
  const float* tr_ln_b  = (const float*)d_in[25];
  const float* tr_b1    = (const float*)d_in[27];
  const float* tr_b2    = (const float*)d_in[29];
  float* out = (float*)d_out;
  char* ws = (char*)d_ws;

  u16* bx  = (u16*)ws;                    // [32768][256] bf16
  u16* fq  = bx + 8388608;                // [32768][1024] bf16 (QKVG fused / h1)
  u16* t_o = fq + 33554432;               // [32768][256] bf16
  u16* pb  = t_o + 8388608;               // permuted pair bias, 2M bf16
  u16* wt  = pb + 2097152;                // transposed weights

  WSrc srcs;
  srcs.p[0] = (const float*)d_in[7];   // row_wq
  srcs.p[1] = (const float*)d_in[8];   // row_wk
  srcs.p[2] = (const float*)d_in[9];   // row_wv
  srcs.p[3] = (const float*)d_in[11];  // row_wg
  srcs.p[4] = (const float*)d_in[13];  // row_wo
  srcs.p[5] = (const float*)d_in[17];  // col_wq
  srcs.p[6] = (const float*)d_in[18];  // col_wk
  srcs.p[7] = (const float*)d_in[19];  // col_wv
  srcs.p[8] = (const float*)d_in[20];  // col_wg
  srcs.p[9] = (const float*)d_in[22];  // col_wo
  srcs.p[10] = (const float*)d_in[26]; // tr_w1
  srcs.p[11] = (const float*)d_in[28]; // tr_w2

  dim3 b256(256);
  transpose_all<<<dim3(4608), b256, 0, stream>>>(srcs, wt);
  pair_bias_kernel<<<dim3(16384), b256, 0, stream>>>(z, row_z_ln_w, row_z_ln_b,
                                                     (const float*)d_in[10], pb);

  // ---- row attention ----
  ln_kernel<<<dim3(8192), b256, 0, stream>>>(m, row_ln_w, row_ln_b, bx);
  gemm128<true,true,false,false,false><<<dim3(8,256), b256, 0, stream>>>(
      bx, wt, row_bg, nullptr, fq, 32768, 1024, 256, 768);
  atten_kernel<256,true><<<dim3(1024), b256, 0, stream>>>(
      fq, fq + 256, fq + 512, fq + 768, pb, m_mask, t_o,
      262144, 1024, 65536, 256, 256, 1);
  gemm128<true,false,false,true,true><<<dim3(2,256), b256, 0, stream>>>(
      t_o, wt + 262144, row_bo, m, out, 32768, 256, 256, 0);

  // ---- column attention ----
  ln_kernel<<<dim3(8192), b256, 0, stream>>>(out, col_ln_w, col_ln_b, bx);
  gemm128<true,true,false,false,false><<<dim3(8,256), b256, 0, stream>>>(
      bx, wt + 327680, col_bg, nullptr, fq, 32768, 1024, 256, 768);
  atten_kernel<128,false><<<dim3(2048), b256, 0, stream>>>(
      fq, fq + 256, fq + 512, fq + 768, nullptr, m_mask, t_o,
      1024, 262144, 256, 65536, 1, 256);
  gemm128<true,false,false,true,true><<<dim3(2,256), b256, 0, stream>>>(
      t_o, wt + 589824, col_bo, out, out, 32768, 256, 256, 0);

  // ---- transition ----
  ln_kernel<<<dim3(8192), b256, 0, stream>>>(out, tr_ln_w, tr_ln_b, bx);
  gemm128<true,false,true,false,false><<<dim3(8,256), b256, 0, stream>>>(
      bx, wt + 655360, tr_b1, nullptr, fq, 32768, 1024, 256, 0);
  gemm128<true,false,false,true,true><<<dim3(2,256), b256, 0, stream>>>(
      fq, wt + 917504, tr_b2, out, out, 32768, 256, 1024, 0);
}

// Round 5
// 314.650 us; speedup vs baseline: 2.1087x; 1.0768x over previous
//
#include <hip/hip_runtime.h>
#include <stdint.h>

#define S_ 128
#define R_ 256
#define CM_ 256
#define H_ 8
#define CA_ 32
#define CZ_ 128

typedef unsigned short u16;
typedef __bf16 bf16x8 __attribute__((ext_vector_type(8)));
typedef float f32x4 __attribute__((ext_vector_type(4)));

__device__ __forceinline__ float bf2f(u16 u){ unsigned v = ((unsigned)u) << 16; float f; __builtin_memcpy(&f, &v, 4); return f; }
__device__ __forceinline__ u16 f2bf(float f){ __bf16 h = (__bf16)f; u16 u; __builtin_memcpy(&u, &h, 2); return u; }
__device__ __forceinline__ unsigned pkbf(float lo, float hi){
  unsigned r; asm("v_cvt_pk_bf16_f32 %0, %1, %2" : "=v"(r) : "v"(lo), "v"(hi)); return r;
}

__device__ __forceinline__ void gl16(const void* g, void* l){
  __builtin_amdgcn_global_load_lds((const __attribute__((address_space(1))) void*)g,
                                   (__attribute__((address_space(3))) void*)l, 16, 0, 0);
}

// ---------------- all 12 weight transposes in one launch ----------------
struct WSrc { const float* p[12]; };
__global__ __launch_bounds__(256) void transpose_all(WSrc srcs, u16* __restrict__ dst){
  int b = blockIdx.x, t = threadIdx.x;
  int job, idx;
  if(b < 2560){ job = b >> 8; idx = ((b & 255) << 8) + t; }
  else if(b < 3584){ job = 10; idx = ((b - 2560) << 8) + t; }
  else { job = 11; idx = ((b - 3584) << 8) + t; }
  int K = (job == 11) ? 1024 : 256;
  int N = (job == 10) ? 1024 : 256;
  int off;
  if(job < 10) off = job * 65536;
  else if(job == 10) off = 655360;
  else off = 917504;
  int k = idx / N, n = idx - k * N;
  float sc = (job == 0 || job == 5) ? 0.17677669529663687f : 1.f;
  dst[off + n * K + k] = f2bf(srcs.p[job][idx] * sc);
}

// ---------------- LayerNorm over last dim 256, fp32 in -> bf16 out ----------------
__global__ __launch_bounds__(256) void ln_kernel(const float* __restrict__ in, const float* __restrict__ w,
                          const float* __restrict__ b, u16* __restrict__ out){
  int wv = threadIdx.x >> 6, lane = threadIdx.x & 63;
  long long row = (long long)blockIdx.x * 4 + wv;
  float4 v = ((const float4*)(in + row * CM_))[lane];
  float s = v.x + v.y + v.z + v.w;
  for(int mo = 32; mo; mo >>= 1) s += __shfl_xor(s, mo, 64);
  float mu = s * (1.f / CM_);
  float dx = v.x - mu, dy = v.y - mu, dz = v.z - mu, dw = v.w - mu;
  float s2 = dx * dx + dy * dy + dz * dz + dw * dw;
  for(int mo = 32; mo; mo >>= 1) s2 += __shfl_xor(s2, mo, 64);
  float rstd = rsqrtf(s2 * (1.f / CM_) + 1e-5f);
  float4 w4 = ((const float4*)w)[lane];
  float4 b4 = ((const float4*)b)[lane];
  ushort4 st;
  st.x = f2bf(dx * rstd * w4.x + b4.x);
  st.y = f2bf(dy * rstd * w4.y + b4.y);
  st.z = f2bf(dz * rstd * w4.z + b4.z);
  st.w = f2bf(dw * rstd * w4.w + b4.w);
  *(ushort4*)(out + row * CM_ + lane * 4) = st;
}

// ---------------- pair bias: LN(z) @ wb -> permuted bf16 [h][qt][kt][lane][r] ----------------
__global__ __launch_bounds__(256) void pair_bias_kernel(const float* __restrict__ z, const float* __restrict__ lnw,
                                 const float* __restrict__ lnb, const float* __restrict__ wb,
                                 u16* __restrict__ pb){
  int wv = threadIdx.x >> 6, lane = threadIdx.x & 63;
  long long row = (long long)blockIdx.x * 4 + wv;        // q*256 + k
  float2 v = ((const float2*)(z + row * CZ_))[lane];
  float s = v.x + v.y;
  for(int mo = 32; mo; mo >>= 1) s += __shfl_xor(s, mo, 64);
  float mu = s * (1.f / CZ_);
  float d0 = v.x - mu, d1 = v.y - mu;
  float s2 = d0 * d0 + d1 * d1;
  for(int mo = 32; mo; mo >>= 1) s2 += __shfl_xor(s2, mo, 64);
  float rstd = rsqrtf(s2 * (1.f / CZ_) + 1e-5f);
  float2 lw = ((const float2*)lnw)[lane], lb = ((const float2*)lnb)[lane];
  float x0 = d0 * rstd * lw.x + lb.x;
  float x1 = d1 * rstd * lw.y + lb.y;
  const float4* wp = (const float4*)(wb + lane * 16);
  float4 w0a = wp[0], w0b = wp[1], w1a = wp[2], w1b = wp[3];
  float acc[8];
  acc[0] = x0 * w0a.x + x1 * w1a.x; acc[1] = x0 * w0a.y + x1 * w1a.y;
  acc[2] = x0 * w0a.z + x1 * w1a.z; acc[3] = x0 * w0a.w + x1 * w1a.w;
  acc[4] = x0 * w0b.x + x1 * w1b.x; acc[5] = x0 * w0b.y + x1 * w1b.y;
  acc[6] = x0 * w0b.z + x1 * w1b.z; acc[7] = x0 * w0b.w + x1 * w1b.w;
  for(int mo = 32; mo; mo >>= 1){
    #pragma unroll
    for(int h = 0; h < 8; h++) acc[h] += __shfl_xor(acc[h], mo, 64);
  }
  if(lane < 8){
    int q = (int)(row >> 8), k = (int)(row & 255);
    int off = (((lane * 16 + (q >> 4)) * 16 + (k >> 4)) << 10)
            + ((((q >> 2) & 3) * 16 + (k & 15)) << 2) + (q & 3);
    pb[off] = f2bf(acc[lane]);
  }
}

// ---------------- MFMA GEMM 128x128 tile, BK=64, global_load_lds + XOR swizzle ----------------
// XCD-aware remap: each XCD owns a contiguous M-strip (A-panel stays in its L2).
template<bool HAS_BIAS, bool HAS_SIG, bool RELU, bool RES, bool F32OUT>
__global__ __launch_bounds__(256) void gemm128(
    const u16* __restrict__ A, const u16* __restrict__ Wt,
    const float* __restrict__ bias, const float* __restrict__ res,
    void* __restrict__ outv, int M, int N, int K, int sigStart){
  __shared__ __attribute__((aligned(16))) unsigned char Ab[16384];
  __shared__ __attribute__((aligned(16))) unsigned char Bb[16384];
  const int t = threadIdx.x;
  const int wv = t >> 6, lane = t & 63, l15 = lane & 15, l4 = lane >> 4;
  const int wm = wv >> 1, wn = wv & 1;
  // bijective XCD remap (gridDim.y divisible by 8)
  const unsigned flat = blockIdx.y * gridDim.x + blockIdx.x;
  const unsigned NB = gridDim.x, mper = gridDim.y >> 3;
  const unsigned xcd = flat & 7, j = flat >> 3;
  const unsigned n_blk = j % NB, m_blk = xcd * mper + j / NB;
  const long long m0 = (long long)m_blk * 128;
  const int n0 = n_blk * 128;
  const int srow = t >> 3;                         // 0..31
  const int ksw  = ((t & 7) ^ (srow & 7)) * 8;     // pre-swizzled k offset (elems)
  const u16* Ag = A  + (m0 + srow) * (long long)K + ksw;
  const u16* Bg = Wt + (long long)(n0 + srow) * K + ksw;
  f32x4 acc[4][4] = {};
  for(int kk = 0; kk < K; kk += 64){
    #pragma unroll
    for(int i = 0; i < 4; i++){
      gl16(Ag + (long long)i * 32 * K + kk, Ab + wv * 1024 + lane * 16 + i * 4096);
      gl16(Bg + (long long)i * 32 * K + kk, Bb + wv * 1024 + lane * 16 + i * 4096);
    }
    asm volatile("s_waitcnt vmcnt(0)" ::: "memory");
    __syncthreads();
    #pragma unroll
    for(int kh = 0; kh < 2; kh++){
      bf16x8 af[4], bq[4];
      #pragma unroll
      for(int mt = 0; mt < 4; mt++){
        int rr = wm * 64 + mt * 16 + l15;
        af[mt] = *(const bf16x8*)(Ab + rr * 128 + ((kh * 64 + l4 * 16) ^ ((rr & 7) << 4)));
      }
      #pragma unroll
      for(int nt = 0; nt < 4; nt++){
        int rr = wn * 64 + nt * 16 + l15;
        bq[nt] = *(const bf16x8*)(Bb + rr * 128 + ((kh * 64 + l4 * 16) ^ ((rr & 7) << 4)));
      }
      #pragma unroll
      for(int mt = 0; mt < 4; mt++)
        #pragma unroll
        for(int nt = 0; nt < 4; nt++)
          acc[mt][nt] = __builtin_amdgcn_mfma_f32_16x16x32_bf16(af[mt], bq[nt], acc[mt][nt], 0, 0, 0);
    }
    __syncthreads();
  }
  // epilogue: row-major issue order so the 4 nt-stores of a row coalesce into 128B
  float bnt[4]; bool sg[4];
  #pragma unroll
  for(int nt = 0; nt < 4; nt++){
    int ncol = n0 + wn * 64 + nt * 16 + l15;
    bnt[nt] = 0.f; sg[nt] = false;
    if(HAS_BIAS){
      if(HAS_SIG){ sg[nt] = (ncol >= sigStart); bnt[nt] = sg[nt] ? bias[ncol - sigStart] : 0.f; }
      else bnt[nt] = bias[ncol];
    }
  }
  #pragma unroll
  for(int mt = 0; mt < 4; mt++){
    #pragma unroll
    for(int r = 0; r < 4; r++){
      long long mrow = m0 + wm * 64 + mt * 16 + l4 * 4 + r;
      #pragma unroll
      for(int nt = 0; nt < 4; nt++){
        int ncol = n0 + wn * 64 + nt * 16 + l15;
        float v = acc[mt][nt][r] + bnt[nt];
        if(HAS_SIG){ if(sg[nt]) v = 1.f / (1.f + __expf(-v)); }
        if(RELU) v = v > 0.f ? v : 0.f;
        if(RES)  v += res[mrow * N + ncol];
        if(F32OUT) ((float*)outv)[mrow * N + ncol] = v;
        else       ((u16*)outv)[mrow * N + ncol] = f2bf(v);
      }
    }
  }
}

// ---------------- fused attention: no-max softmax, chunk-permuted P, gated epilogue ----
// Key permutation k' = (kt>>2)*64 + (k&15)*4 + (kt&3), applied to both P cols and V^T rows.
template<int L, bool HAS_BIAS>
__global__ __launch_bounds__(256) void atten_kernel(
    const u16* __restrict__ qg, const u16* __restrict__ kg, const u16* __restrict__ vg,
    const u16* __restrict__ gg, const u16* __restrict__ pb, const float* __restrict__ mask,
    u16* __restrict__ og,
    long long obase_mul, long long tstride, long long obase_o, long long ostride,
    long long mbase_mul, int mstride){
  __shared__ __attribute__((aligned(16))) unsigned char smem[L * 128 + 8192];
  unsigned char* Kl = smem;              // [L][32] bf16, XOR swizzle
  unsigned char* Vt = smem + L * 64;     // [32][L] bf16 (V^T, k-permuted), swizzled
  unsigned char* Pl = smem + L * 128;    // per-wave [16][64] bf16 chunk

  const int t = threadIdx.x;
  const int wv = t >> 6, lane = t & 63, l15 = lane & 15, l4 = lane >> 4;
  const int h = blockIdx.x & 7;
  const int outer = blockIdx.x >> 3;
  const long long base  = (long long)outer * obase_mul + h * CA_;
  const long long baseo = (long long)outer * obase_o  + h * CA_;
  const long long mb = (long long)outer * mbase_mul;
  const int KT = L / 16, NC = L / 64;

  #pragma unroll
  for(int j = 0; j < L * 4; j += 256){
    int cid = j + t;
    int row = cid >> 2, ko = cid & 3;
    int4 kv = *(const int4*)(kg + base + (long long)row * tstride + ko * 8);
    *(int4*)(Kl + ((row * 64 + ko * 16) ^ ((row & 7) << 4))) = kv;
  }
  if(t < L){
    __attribute__((aligned(16))) u16 tmp[32];
    const u16* vp = vg + base + (long long)t * tstride;
    #pragma unroll
    for(int j2 = 0; j2 < 4; j2++) ((int4*)tmp)[j2] = *(const int4*)(vp + j2 * 8);
    int kp = (t >> 6) * 64 + (t & 15) * 4 + ((t >> 4) & 3);   // permuted key index
    #pragma unroll
    for(int c = 0; c < 32; c++)
      *(u16*)(Vt + (((c * L + kp) * 2) ^ ((c & 7) << 4))) = tmp[c];
  }
  __syncthreads();

  float mskb[L / 16];
  #pragma unroll
  for(int kt = 0; kt < KT; kt++)
    mskb[kt] = (mask[mb + (long long)(kt * 16 + l15) * mstride] - 1.f) * 1e9f;

  unsigned char* Pw = Pl + wv * 2048;
  const int NQ = L / 4;
  #pragma unroll
  for(int qt = 0; qt < NQ / 16; qt++){
    const int qrow0 = wv * NQ + qt * 16;
    bf16x8 aq = *(const bf16x8*)(qg + base + (long long)(qrow0 + l15) * tstride + l4 * 8);
    f32x4 lac[L / 16];
    #pragma unroll
    for(int kt = 0; kt < KT; kt++){
      int kr = kt * 16 + l15;
      bf16x8 bk = *(const bf16x8*)(Kl + ((kr * 64 + l4 * 16) ^ ((kr & 7) << 4)));
      f32x4 zz = {0.f, 0.f, 0.f, 0.f};
      lac[kt] = __builtin_amdgcn_mfma_f32_16x16x32_bf16(aq, bk, zz, 0, 0, 0);
    }
    // merged bias + mask + exp + sum (no max-subtract: |logit| <~8 by construction)
    const u16* tile = HAS_BIAS ? (pb + (((h * 16 + (qrow0 >> 4)) * 16) << 10) + lane * 4) : nullptr;
    float sm[4] = {1e-30f, 1e-30f, 1e-30f, 1e-30f};
    #pragma unroll
    for(int kt = 0; kt < KT; kt++){
      float mm = mskb[kt];
      if(HAS_BIAS){
        ushort4 b4 = *(const ushort4*)(tile + (kt << 10));
        lac[kt][0] = __expf(lac[kt][0] + mm + bf2f(b4.x));
        lac[kt][1] = __expf(lac[kt][1] + mm + bf2f(b4.y));
        lac[kt][2] = __expf(lac[kt][2] + mm + bf2f(b4.z));
        lac[kt][3] = __expf(lac[kt][3] + mm + bf2f(b4.w));
      } else {
        #pragma unroll
        for(int r = 0; r < 4; r++) lac[kt][r] = __expf(lac[kt][r] + mm);
      }
      #pragma unroll
      for(int r = 0; r < 4; r++) sm[r] += lac[kt][r];
    }
    #pragma unroll
    for(int mo = 1; mo < 16; mo <<= 1)
      #pragma unroll
      for(int r = 0; r < 4; r++) sm[r] += __shfl_xor(sm[r], mo, 64);
    float inv[4];
    #pragma unroll
    for(int r = 0; r < 4; r++) inv[r] = 1.f / sm[r];
    // chunked PV on unnormalized P; lane's 4 chunk-values are contiguous at col l15*4
    f32x4 oac[2] = {{0,0,0,0},{0,0,0,0}};
    #pragma unroll
    for(int ch = 0; ch < NC; ch++){
      asm volatile("" ::: "memory");
      #pragma unroll
      for(int r = 0; r < 4; r++){
        int qp = l4 * 4 + r;
        uint2 pk2;
        pk2.x = pkbf(lac[ch * 4 + 0][r], lac[ch * 4 + 1][r]);
        pk2.y = pkbf(lac[ch * 4 + 2][r], lac[ch * 4 + 3][r]);
        *(uint2*)(Pw + qp * 128 + ((l15 * 8) ^ ((qp & 7) << 4))) = pk2;
      }
      asm volatile("s_waitcnt lgkmcnt(0)" ::: "memory");
      #pragma unroll
      for(int ksl = 0; ksl < 2; ksl++){
        bf16x8 ap = *(const bf16x8*)(Pw + l15 * 128 + ((ksl * 64 + l4 * 16) ^ ((l15 & 7) << 4)));
        #pragma unroll
        for(int ct = 0; ct < 2; ct++){
          int c = ct * 16 + l15;
          bf16x8 bv = *(const bf16x8*)(Vt + (((c * L + ch * 64 + ksl * 32 + l4 * 8) * 2) ^ ((c & 7) << 4)));
          oac[ct] = __builtin_amdgcn_mfma_f32_16x16x32_bf16(ap, bv, oac[ct], 0, 0, 0);
        }
      }
    }
    // epilogue: normalize, multiply sigmoid-gate, store
    #pragma unroll
    for(int ct = 0; ct < 2; ct++)
      #pragma unroll
      for(int r = 0; r < 4; r++){
        int qi = qrow0 + l4 * 4 + r, c = ct * 16 + l15;
        float g = bf2f(gg[base + (long long)qi * tstride + c]);
        og[baseo + (long long)qi * ostride + c] = f2bf(oac[ct][r] * inv[r] * g);
      }
  }
}

extern "C" void kernel_launch(void* const* d_in, const int* in_sizes, int n_in,
                              void* d_out, int out_size, void* d_ws, size_t ws_size,
                              hipStream_t stream){
  const float* m        = (const float*)d_in[0];
  const float* m_mask   = (const float*)d_in[1];
  const float* z        = (const float*)d_in[2];
  const float* row_ln_w = (const float*)d_in[3];
  const float* row_ln_b = (const float*)d_in[4];
  const float* row_z_ln_w = (const float*)d_in[5];
  const float* row_z_ln_b = (const float*)d_in[6];
  const float* row_bg   = (const float*)d_in[12];
  const float* row_bo   = (const float*)d_in[14];
  const float* col_ln_w = (const float*)d_in[15];
  const float* col_ln_b = (const float*)d_in[16];
  const float* col_bg   = (const float*)d_in[21];
  const float* col_bo   = (const float*)d_in[23];
  const float* tr_ln_w  = (const float*)d_in[24];
  const float* tr_ln_b  = (const float*)d_in[25];
  const float* tr_b1    = (const float*)d_in[27];
  const float* tr_b2    = (const float*)d_in[29];
  float* out = (float*)d_out;
  char* ws = (char*)d_ws;

  u16* bx  = (u16*)ws;                    // [32768][256] bf16
  u16* fq  = bx + 8388608;                // [32768][1024] bf16 (QKVG fused / h1)
  u16* t_o = fq + 33554432;               // [32768][256] bf16
  u16* pb  = t_o + 8388608;               // permuted pair bias, 2M bf16
  u16* wt  = pb + 2097152;                // transposed weights

  WSrc srcs;
  srcs.p[0] = (const float*)d_in[7];   // row_wq
  srcs.p[1] = (const float*)d_in[8];   // row_wk
  srcs.p[2] = (const float*)d_in[9];   // row_wv
  srcs.p[3] = (const float*)d_in[11];  // row_wg
  srcs.p[4] = (const float*)d_in[13];  // row_wo
  srcs.p[5] = (const float*)d_in[17];  // col_wq
  srcs.p[6] = (const float*)d_in[18];  // col_wk
  srcs.p[7] = (const float*)d_in[19];  // col_wv
  srcs.p[8] = (const float*)d_in[20];  // col_wg
  srcs.p[9] = (const float*)d_in[22];  // col_wo
  srcs.p[10] = (const float*)d_in[26]; // tr_w1
  srcs.p[11] = (const float*)d_in[28]; // tr_w2

  dim3 b256(256);
  transpose_all<<<dim3(4608), b256, 0, stream>>>(srcs, wt);
  pair_bias_kernel<<<dim3(16384), b256, 0, stream>>>(z, row_z_ln_w, row_z_ln_b,
                                                     (const float*)d_in[10], pb);

  // ---- row attention ----
  ln_kernel<<<dim3(8192), b256, 0, stream>>>(m, row_ln_w, row_ln_b, bx);
  gemm128<true,true,false,false,false><<<dim3(8,256), b256, 0, stream>>>(
      bx, wt, row_bg, nullptr, fq, 32768, 1024, 256, 768);
  atten_kernel<256,true><<<dim3(1024), b256, 0, stream>>>(
      fq, fq + 256, fq + 512, fq + 768, pb, m_mask, t_o,
      262144, 1024, 65536, 256, 256, 1);
  gemm128<true,false,false,true,true><<<dim3(2,256), b256, 0, stream>>>(
      t_o, wt + 262144, row_bo, m, out, 32768, 256, 256, 0);

  // ---- column attention ----
  ln_kernel<<<dim3(8192), b256, 0, stream>>>(out, col_ln_w, col_ln_b, bx);
  gemm128<true,true,false,false,false><<<dim3(8,256), b256, 0, stream>>>(
      bx, wt + 327680, col_bg, nullptr, fq, 32768, 1024, 256, 768);
  atten_kernel<128,false><<<dim3(2048), b256, 0, stream>>>(
      fq, fq + 256, fq + 512, fq + 768, nullptr, m_mask, t_o,
      1024, 262144, 256, 65536, 1, 256);
  gemm128<true,false,false,true,true><<<dim3(2,256), b256, 0, stream>>>(
      t_o, wt + 589824, col_bo, out, out, 32768, 256, 256, 0);

  // ---- transition ----
  ln_kernel<<<dim3(8192), b256, 0, stream>>>(out, tr_ln_w, tr_ln_b, bx);
  gemm128<true,false,true,false,false><<<dim3(8,256), b256, 0, stream>>>(
      bx, wt + 655360, tr_b1, nullptr, fq, 32768, 1024, 256, 0);
  gemm128<true,false,false,true,true><<<dim3(2,256), b256, 0, stream>>>(
      fq, wt + 917504, tr_b2, out, out, 32768, 256, 1024, 0);
}

// Round 6
// 283.549 us; speedup vs baseline: 2.3400x; 1.1097x over previous
//
#include <hip/hip_runtime.h>
#include <stdint.h>

#define S_ 128
#define R_ 256
#define CM_ 256
#define H_ 8
#define CA_ 32
#define CZ_ 128

typedef unsigned short u16;
typedef __bf16 bf16x8 __attribute__((ext_vector_type(8)));
typedef float f32x4 __attribute__((ext_vector_type(4)));

__device__ __forceinline__ float bf2f(u16 u){ unsigned v = ((unsigned)u) << 16; float f; __builtin_memcpy(&f, &v, 4); return f; }
__device__ __forceinline__ u16 f2bf(float f){ __bf16 h = (__bf16)f; u16 u; __builtin_memcpy(&u, &h, 2); return u; }
__device__ __forceinline__ unsigned pkbf(float lo, float hi){
  unsigned r; asm("v_cvt_pk_bf16_f32 %0, %1, %2" : "=v"(r) : "v"(lo), "v"(hi)); return r;
}

__device__ __forceinline__ void gl16(const void* g, void* l){
  __builtin_amdgcn_global_load_lds((const __attribute__((address_space(1))) void*)g,
                                   (__attribute__((address_space(3))) void*)l, 16, 0, 0);
}

// ---------------- all 12 weight transposes in one launch ----------------
struct WSrc { const float* p[12]; };
__global__ __launch_bounds__(256) void transpose_all(WSrc srcs, u16* __restrict__ dst){
  int b = blockIdx.x, t = threadIdx.x;
  int job, idx;
  if(b < 2560){ job = b >> 8; idx = ((b & 255) << 8) + t; }
  else if(b < 3584){ job = 10; idx = ((b - 2560) << 8) + t; }
  else { job = 11; idx = ((b - 3584) << 8) + t; }
  int K = (job == 11) ? 1024 : 256;
  int N = (job == 10) ? 1024 : 256;
  int off;
  if(job < 10) off = job * 65536;
  else if(job == 10) off = 655360;
  else off = 917504;
  int k = idx / N, n = idx - k * N;
  float sc = (job == 0 || job == 5) ? 0.17677669529663687f : 1.f;
  dst[off + n * K + k] = f2bf(srcs.p[job][idx] * sc);
}

// ---------------- LayerNorm over last dim 256, fp32 in -> bf16 out ----------------
__global__ __launch_bounds__(256) void ln_kernel(const float* __restrict__ in, const float* __restrict__ w,
                          const float* __restrict__ b, u16* __restrict__ out){
  int wv = threadIdx.x >> 6, lane = threadIdx.x & 63;
  long long row = (long long)blockIdx.x * 4 + wv;
  float4 v = ((const float4*)(in + row * CM_))[lane];
  float s = v.x + v.y + v.z + v.w;
  for(int mo = 32; mo; mo >>= 1) s += __shfl_xor(s, mo, 64);
  float mu = s * (1.f / CM_);
  float dx = v.x - mu, dy = v.y - mu, dz = v.z - mu, dw = v.w - mu;
  float s2 = dx * dx + dy * dy + dz * dz + dw * dw;
  for(int mo = 32; mo; mo >>= 1) s2 += __shfl_xor(s2, mo, 64);
  float rstd = rsqrtf(s2 * (1.f / CM_) + 1e-5f);
  float4 w4 = ((const float4*)w)[lane];
  float4 b4 = ((const float4*)b)[lane];
  ushort4 st;
  st.x = f2bf(dx * rstd * w4.x + b4.x);
  st.y = f2bf(dy * rstd * w4.y + b4.y);
  st.z = f2bf(dz * rstd * w4.z + b4.z);
  st.w = f2bf(dw * rstd * w4.w + b4.w);
  *(ushort4*)(out + row * CM_ + lane * 4) = st;
}

// ---------------- pair bias v2: LN(z) -> LDS -> MFMA @ wb -> permuted bf16 ----------------
// Block = 32 z-rows. LN: 8 lanes/row (3+3 shfl levels). Projection: 8 MFMA (2 waves x 4 K-steps).
__global__ __launch_bounds__(256) void pair_bias_kernel(const float* __restrict__ z, const float* __restrict__ lnw,
                                 const float* __restrict__ lnb, const float* __restrict__ wb,
                                 u16* __restrict__ pb){
  __shared__ __attribute__((aligned(16))) unsigned char Xl[32 * 256];  // [32][128] bf16, XOR swz
  __shared__ __attribute__((aligned(16))) unsigned char Wl[16 * 256];  // [16 n][128 k] bf16, XOR swz
  const int t = threadIdx.x;
  const int wv = t >> 6, lane = t & 63, l15 = lane & 15, l4 = lane >> 4;
  const int r0 = blockIdx.x * 32;

  // stage wb -> Wl (transposed [n][k], heads 8..15 zero-padded)
  if(t < 128){
    const float4* wr = (const float4*)(wb + t * 8);
    float4 a = wr[0], bq = wr[1];
    u16 vals[8] = {f2bf(a.x), f2bf(a.y), f2bf(a.z), f2bf(a.w),
                   f2bf(bq.x), f2bf(bq.y), f2bf(bq.z), f2bf(bq.w)};
    #pragma unroll
    for(int n = 0; n < 8; n++){
      *(u16*)(Wl + ((n * 256 + t * 2) ^ ((n & 7) << 4))) = vals[n];
      *(u16*)(Wl + (((n + 8) * 256 + t * 2) ^ ((n & 7) << 4))) = 0;
    }
  }
  // LN: row = wv*8 + (lane>>3), 16 c per lane
  {
    int row = wv * 8 + (lane >> 3);
    int c0 = (lane & 7) * 16;
    const float4* rp = (const float4*)(z + (long long)(r0 + row) * CZ_ + c0);
    float4 v0 = rp[0], v1 = rp[1], v2 = rp[2], v3 = rp[3];
    float s = v0.x + v0.y + v0.z + v0.w + v1.x + v1.y + v1.z + v1.w
            + v2.x + v2.y + v2.z + v2.w + v3.x + v3.y + v3.z + v3.w;
    s += __shfl_xor(s, 1, 64); s += __shfl_xor(s, 2, 64); s += __shfl_xor(s, 4, 64);
    float mu = s * (1.f / CZ_);
    float d[16] = {v0.x - mu, v0.y - mu, v0.z - mu, v0.w - mu,
                   v1.x - mu, v1.y - mu, v1.z - mu, v1.w - mu,
                   v2.x - mu, v2.y - mu, v2.z - mu, v2.w - mu,
                   v3.x - mu, v3.y - mu, v3.z - mu, v3.w - mu};
    float s2 = 0.f;
    #pragma unroll
    for(int i = 0; i < 16; i++) s2 += d[i] * d[i];
    s2 += __shfl_xor(s2, 1, 64); s2 += __shfl_xor(s2, 2, 64); s2 += __shfl_xor(s2, 4, 64);
    float rstd = rsqrtf(s2 * (1.f / CZ_) + 1e-5f);
    const float4* wp = (const float4*)(lnw + c0);
    const float4* bp = (const float4*)(lnb + c0);
    float x[16];
    #pragma unroll
    for(int i = 0; i < 4; i++){
      float4 w4 = wp[i], b4 = bp[i];
      x[i * 4 + 0] = d[i * 4 + 0] * rstd * w4.x + b4.x;
      x[i * 4 + 1] = d[i * 4 + 1] * rstd * w4.y + b4.y;
      x[i * 4 + 2] = d[i * 4 + 2] * rstd * w4.z + b4.z;
      x[i * 4 + 3] = d[i * 4 + 3] * rstd * w4.w + b4.w;
    }
    uint4 p0, p1;
    p0.x = pkbf(x[0], x[1]);  p0.y = pkbf(x[2], x[3]);
    p0.z = pkbf(x[4], x[5]);  p0.w = pkbf(x[6], x[7]);
    p1.x = pkbf(x[8], x[9]);  p1.y = pkbf(x[10], x[11]);
    p1.z = pkbf(x[12], x[13]); p1.w = pkbf(x[14], x[15]);
    *(uint4*)(Xl + ((row * 256 + c0 * 2) ^ ((row & 7) << 4))) = p0;
    *(uint4*)(Xl + ((row * 256 + c0 * 2 + 16) ^ ((row & 7) << 4))) = p1;
  }
  __syncthreads();
  // MFMA projection: waves 0,1 each do a 16-row tile x 4 K-steps
  if(wv < 2){
    f32x4 acc = {0.f, 0.f, 0.f, 0.f};
    #pragma unroll
    for(int ks = 0; ks < 4; ks++){
      int rowA = wv * 16 + l15;
      bf16x8 a = *(const bf16x8*)(Xl + ((rowA * 256 + l4 * 16 + ks * 64) ^ ((rowA & 7) << 4)));
      bf16x8 b = *(const bf16x8*)(Wl + ((l15 * 256 + l4 * 16 + ks * 64) ^ ((l15 & 7) << 4)));
      acc = __builtin_amdgcn_mfma_f32_16x16x32_bf16(a, b, acc, 0, 0, 0);
    }
    if(l15 < 8){
      #pragma unroll
      for(int r = 0; r < 4; r++){
        int rowg = r0 + wv * 16 + l4 * 4 + r;
        int q = rowg >> 8, k = rowg & 255;
        int off = (((l15 * 16 + (q >> 4)) * 16 + (k >> 4)) << 10)
                + ((((q >> 2) & 3) * 16 + (k & 15)) << 2) + (q & 3);
        pb[off] = f2bf(acc[r]);
      }
    }
  }
}

// ---------------- MFMA GEMM 128x128 tile, BK=64, global_load_lds + XOR swizzle ----------------
// XCD-aware remap: each XCD owns a contiguous M-strip (A-panel stays in its L2).
template<bool HAS_BIAS, bool HAS_SIG, bool RELU, bool RES, bool F32OUT>
__global__ __launch_bounds__(256) void gemm128(
    const u16* __restrict__ A, const u16* __restrict__ Wt,
    const float* __restrict__ bias, const float* __restrict__ res,
    void* __restrict__ outv, int M, int N, int K, int sigStart){
  __shared__ __attribute__((aligned(16))) unsigned char Ab[16384];
  __shared__ __attribute__((aligned(16))) unsigned char Bb[16384];
  const int t = threadIdx.x;
  const int wv = t >> 6, lane = t & 63, l15 = lane & 15, l4 = lane >> 4;
  const int wm = wv >> 1, wn = wv & 1;
  // bijective XCD remap (gridDim.y divisible by 8)
  const unsigned flat = blockIdx.y * gridDim.x + blockIdx.x;
  const unsigned NB = gridDim.x, mper = gridDim.y >> 3;
  const unsigned xcd = flat & 7, j = flat >> 3;
  const unsigned n_blk = j % NB, m_blk = xcd * mper + j / NB;
  const long long m0 = (long long)m_blk * 128;
  const int n0 = n_blk * 128;
  const int srow = t >> 3;                         // 0..31
  const int ksw  = ((t & 7) ^ (srow & 7)) * 8;     // pre-swizzled k offset (elems)
  const u16* Ag = A  + (m0 + srow) * (long long)K + ksw;
  const u16* Bg = Wt + (long long)(n0 + srow) * K + ksw;
  f32x4 acc[4][4] = {};
  for(int kk = 0; kk < K; kk += 64){
    #pragma unroll
    for(int i = 0; i < 4; i++){
      gl16(Ag + (long long)i * 32 * K + kk, Ab + wv * 1024 + lane * 16 + i * 4096);
      gl16(Bg + (long long)i * 32 * K + kk, Bb + wv * 1024 + lane * 16 + i * 4096);
    }
    asm volatile("s_waitcnt vmcnt(0)" ::: "memory");
    __syncthreads();
    #pragma unroll
    for(int kh = 0; kh < 2; kh++){
      bf16x8 af[4], bq[4];
      #pragma unroll
      for(int mt = 0; mt < 4; mt++){
        int rr = wm * 64 + mt * 16 + l15;
        af[mt] = *(const bf16x8*)(Ab + rr * 128 + ((kh * 64 + l4 * 16) ^ ((rr & 7) << 4)));
      }
      #pragma unroll
      for(int nt = 0; nt < 4; nt++){
        int rr = wn * 64 + nt * 16 + l15;
        bq[nt] = *(const bf16x8*)(Bb + rr * 128 + ((kh * 64 + l4 * 16) ^ ((rr & 7) << 4)));
      }
      #pragma unroll
      for(int mt = 0; mt < 4; mt++)
        #pragma unroll
        for(int nt = 0; nt < 4; nt++)
          acc[mt][nt] = __builtin_amdgcn_mfma_f32_16x16x32_bf16(af[mt], bq[nt], acc[mt][nt], 0, 0, 0);
    }
    __syncthreads();
  }
  // epilogue: row-major issue order so the 4 nt-stores of a row coalesce into 128B
  float bnt[4]; bool sg[4];
  #pragma unroll
  for(int nt = 0; nt < 4; nt++){
    int ncol = n0 + wn * 64 + nt * 16 + l15;
    bnt[nt] = 0.f; sg[nt] = false;
    if(HAS_BIAS){
      if(HAS_SIG){ sg[nt] = (ncol >= sigStart); bnt[nt] = sg[nt] ? bias[ncol - sigStart] : 0.f; }
      else bnt[nt] = bias[ncol];
    }
  }
  #pragma unroll
  for(int mt = 0; mt < 4; mt++){
    #pragma unroll
    for(int r = 0; r < 4; r++){
      long long mrow = m0 + wm * 64 + mt * 16 + l4 * 4 + r;
      #pragma unroll
      for(int nt = 0; nt < 4; nt++){
        int ncol = n0 + wn * 64 + nt * 16 + l15;
        float v = acc[mt][nt][r] + bnt[nt];
        if(HAS_SIG){ if(sg[nt]) v = 1.f / (1.f + __expf(-v)); }
        if(RELU) v = v > 0.f ? v : 0.f;
        if(RES)  v += res[mrow * N + ncol];
        if(F32OUT) ((float*)outv)[mrow * N + ncol] = v;
        else       ((u16*)outv)[mrow * N + ncol] = f2bf(v);
      }
    }
  }
}

// ---------------- fused attention: no-max softmax, chunk-permuted P, gated epilogue ----
// Key permutation k' = (kt>>2)*64 + (k&15)*4 + (kt&3), applied to both P cols and V^T rows.
template<int L, bool HAS_BIAS>
__global__ __launch_bounds__(256) void atten_kernel(
    const u16* __restrict__ qg, const u16* __restrict__ kg, const u16* __restrict__ vg,
    const u16* __restrict__ gg, const u16* __restrict__ pb, const float* __restrict__ mask,
    u16* __restrict__ og,
    long long obase_mul, long long tstride, long long obase_o, long long ostride,
    long long mbase_mul, int mstride){
  __shared__ __attribute__((aligned(16))) unsigned char smem[L * 128 + 8192];
  unsigned char* Kl = smem;              // [L][32] bf16, XOR swizzle
  unsigned char* Vt = smem + L * 64;     // [32][L] bf16 (V^T, k-permuted), swizzled
  unsigned char* Pl = smem + L * 128;    // per-wave [16][64] bf16 chunk

  const int t = threadIdx.x;
  const int wv = t >> 6, lane = t & 63, l15 = lane & 15, l4 = lane >> 4;
  const int h = blockIdx.x & 7;
  const int outer = blockIdx.x >> 3;
  const long long base  = (long long)outer * obase_mul + h * CA_;
  const long long baseo = (long long)outer * obase_o  + h * CA_;
  const long long mb = (long long)outer * mbase_mul;
  const int KT = L / 16, NC = L / 64;

  #pragma unroll
  for(int j = 0; j < L * 4; j += 256){
    int cid = j + t;
    int row = cid >> 2, ko = cid & 3;
    int4 kv = *(const int4*)(kg + base + (long long)row * tstride + ko * 8);
    *(int4*)(Kl + ((row * 64 + ko * 16) ^ ((row & 7) << 4))) = kv;
  }
  if(t < L){
    __attribute__((aligned(16))) u16 tmp[32];
    const u16* vp = vg + base + (long long)t * tstride;
    #pragma unroll
    for(int j2 = 0; j2 < 4; j2++) ((int4*)tmp)[j2] = *(const int4*)(vp + j2 * 8);
    int kp = (t >> 6) * 64 + (t & 15) * 4 + ((t >> 4) & 3);   // permuted key index
    #pragma unroll
    for(int c = 0; c < 32; c++)
      *(u16*)(Vt + (((c * L + kp) * 2) ^ ((c & 7) << 4))) = tmp[c];
  }
  __syncthreads();

  float mskb[L / 16];
  #pragma unroll
  for(int kt = 0; kt < KT; kt++)
    mskb[kt] = (mask[mb + (long long)(kt * 16 + l15) * mstride] - 1.f) * 1e9f;

  unsigned char* Pw = Pl + wv * 2048;
  const int NQ = L / 4;
  #pragma unroll
  for(int qt = 0; qt < NQ / 16; qt++){
    const int qrow0 = wv * NQ + qt * 16;
    bf16x8 aq = *(const bf16x8*)(qg + base + (long long)(qrow0 + l15) * tstride + l4 * 8);
    f32x4 lac[L / 16];
    #pragma unroll
    for(int kt = 0; kt < KT; kt++){
      int kr = kt * 16 + l15;
      bf16x8 bk = *(const bf16x8*)(Kl + ((kr * 64 + l4 * 16) ^ ((kr & 7) << 4)));
      f32x4 zz = {0.f, 0.f, 0.f, 0.f};
      lac[kt] = __builtin_amdgcn_mfma_f32_16x16x32_bf16(aq, bk, zz, 0, 0, 0);
    }
    // merged bias + mask + exp + sum (no max-subtract: |logit| <~8 by construction)
    const u16* tile = HAS_BIAS ? (pb + (((h * 16 + (qrow0 >> 4)) * 16) << 10) + lane * 4) : nullptr;
    float sm[4] = {1e-30f, 1e-30f, 1e-30f, 1e-30f};
    #pragma unroll
    for(int kt = 0; kt < KT; kt++){
      float mm = mskb[kt];
      if(HAS_BIAS){
        ushort4 b4 = *(const ushort4*)(tile + (kt << 10));
        lac[kt][0] = __expf(lac[kt][0] + mm + bf2f(b4.x));
        lac[kt][1] = __expf(lac[kt][1] + mm + bf2f(b4.y));
        lac[kt][2] = __expf(lac[kt][2] + mm + bf2f(b4.z));
        lac[kt][3] = __expf(lac[kt][3] + mm + bf2f(b4.w));
      } else {
        #pragma unroll
        for(int r = 0; r < 4; r++) lac[kt][r] = __expf(lac[kt][r] + mm);
      }
      #pragma unroll
      for(int r = 0; r < 4; r++) sm[r] += lac[kt][r];
    }
    #pragma unroll
    for(int mo = 1; mo < 16; mo <<= 1)
      #pragma unroll
      for(int r = 0; r < 4; r++) sm[r] += __shfl_xor(sm[r], mo, 64);
    float inv[4];
    #pragma unroll
    for(int r = 0; r < 4; r++) inv[r] = 1.f / sm[r];
    // chunked PV on unnormalized P; lane's 4 chunk-values are contiguous at col l15*4
    f32x4 oac[2] = {{0,0,0,0},{0,0,0,0}};
    #pragma unroll
    for(int ch = 0; ch < NC; ch++){
      asm volatile("" ::: "memory");
      #pragma unroll
      for(int r = 0; r < 4; r++){
        int qp = l4 * 4 + r;
        uint2 pk2;
        pk2.x = pkbf(lac[ch * 4 + 0][r], lac[ch * 4 + 1][r]);
        pk2.y = pkbf(lac[ch * 4 + 2][r], lac[ch * 4 + 3][r]);
        *(uint2*)(Pw + qp * 128 + ((l15 * 8) ^ ((qp & 7) << 4))) = pk2;
      }
      asm volatile("s_waitcnt lgkmcnt(0)" ::: "memory");
      #pragma unroll
      for(int ksl = 0; ksl < 2; ksl++){
        bf16x8 ap = *(const bf16x8*)(Pw + l15 * 128 + ((ksl * 64 + l4 * 16) ^ ((l15 & 7) << 4)));
        #pragma unroll
        for(int ct = 0; ct < 2; ct++){
          int c = ct * 16 + l15;
          bf16x8 bv = *(const bf16x8*)(Vt + (((c * L + ch * 64 + ksl * 32 + l4 * 8) * 2) ^ ((c & 7) << 4)));
          oac[ct] = __builtin_amdgcn_mfma_f32_16x16x32_bf16(ap, bv, oac[ct], 0, 0, 0);
        }
      }
    }
    // epilogue: normalize, multiply sigmoid-gate, store
    #pragma unroll
    for(int ct = 0; ct < 2; ct++)
      #pragma unroll
      for(int r = 0; r < 4; r++){
        int qi = qrow0 + l4 * 4 + r, c = ct * 16 + l15;
        float g = bf2f(gg[base + (long long)qi * tstride + c]);
        og[baseo + (long long)qi * ostride + c] = f2bf(oac[ct][r] * inv[r] * g);
      }
  }
}

extern "C" void kernel_launch(void* const* d_in, const int* in_sizes, int n_in,
                              void* d_out, int out_size, void* d_ws, size_t ws_size,
                              hipStream_t stream){
  const float* m        = (const float*)d_in[0];
  const float* m_mask   = (const float*)d_in[1];
  const float* z        = (const float*)d_in[2];
  const float* row_ln_w = (const float*)d_in[3];
  const float* row_ln_b = (const float*)d_in[4];
  const float* row_z_ln_w = (const float*)d_in[5];
  const float* row_z_ln_b = (const float*)d_in[6];
  const float* row_bg   = (const float*)d_in[12];
  const float* row_bo   = (const float*)d_in[14];
  const float* col_ln_w = (const float*)d_in[15];
  const float* col_ln_b = (const float*)d_in[16];
  const float* col_bg   = (const float*)d_in[21];
  const float* col_bo   = (const float*)d_in[23];
  const float* tr_ln_w  = (const float*)d_in[24];
  const float* tr_ln_b  = (const float*)d_in[25];
  const float* tr_b1    = (const float*)d_in[27];
  const float* tr_b2    = (const float*)d_in[29];
  float* out = (float*)d_out;
  char* ws = (char*)d_ws;

  u16* bx  = (u16*)ws;                    // [32768][256] bf16
  u16* fq  = bx + 8388608;                // [32768][1024] bf16 (QKVG fused / h1)
  u16* t_o = fq + 33554432;               // [32768][256] bf16
  u16* pb  = t_o + 8388608;               // permuted pair bias, 2M bf16
  u16* wt  = pb + 2097152;                // transposed weights

  WSrc srcs;
  srcs.p[0] = (const float*)d_in[7];   // row_wq
  srcs.p[1] = (const float*)d_in[8];   // row_wk
  srcs.p[2] = (const float*)d_in[9];   // row_wv
  srcs.p[3] = (const float*)d_in[11];  // row_wg
  srcs.p[4] = (const float*)d_in[13];  // row_wo
  srcs.p[5] = (const float*)d_in[17];  // col_wq
  srcs.p[6] = (const float*)d_in[18];  // col_wk
  srcs.p[7] = (const float*)d_in[19];  // col_wv
  srcs.p[8] = (const float*)d_in[20];  // col_wg
  srcs.p[9] = (const float*)d_in[22];  // col_wo
  srcs.p[10] = (const float*)d_in[26]; // tr_w1
  srcs.p[11] = (const float*)d_in[28]; // tr_w2

  dim3 b256(256);
  transpose_all<<<dim3(4608), b256, 0, stream>>>(srcs, wt);
  pair_bias_kernel<<<dim3(2048), b256, 0, stream>>>(z, row_z_ln_w, row_z_ln_b,
                                                    (const float*)d_in[10], pb);

  // ---- row attention ----
  ln_kernel<<<dim3(8192), b256, 0, stream>>>(m, row_ln_w, row_ln_b, bx);
  gemm128<true,true,false,false,false><<<dim3(8,256), b256, 0, stream>>>(
      bx, wt, row_bg, nullptr, fq, 32768, 1024, 256, 768);
  atten_kernel<256,true><<<dim3(1024), b256, 0, stream>>>(
      fq, fq + 256, fq + 512, fq + 768, pb, m_mask, t_o,
      262144, 1024, 65536, 256, 256, 1);
  gemm128<true,false,false,true,true><<<dim3(2,256), b256, 0, stream>>>(
      t_o, wt + 262144, row_bo, m, out, 32768, 256, 256, 0);

  // ---- column attention ----
  ln_kernel<<<dim3(8192), b256, 0, stream>>>(out, col_ln_w, col_ln_b, bx);
  gemm128<true,true,false,false,false><<<dim3(8,256), b256, 0, stream>>>(
      bx, wt + 327680, col_bg, nullptr, fq, 32768, 1024, 256, 768);
  atten_kernel<128,false><<<dim3(2048), b256, 0, stream>>>(
      fq, fq + 256, fq + 512, fq + 768, nullptr, m_mask, t_o,
      1024, 262144, 256, 65536, 1, 256);
  gemm128<true,false,false,true,true><<<dim3(2,256), b256, 0, stream>>>(
      t_o, wt + 589824, col_bo, out, out, 32768, 256, 256, 0);

  // ---- transition ----
  ln_kernel<<<dim3(8192), b256, 0, stream>>>(out, tr_ln_w, tr_ln_b, bx);
  gemm128<true,false,true,false,false><<<dim3(8,256), b256, 0, stream>>>(
      bx, wt + 655360, tr_b1, nullptr, fq, 32768, 1024, 256, 0);
  gemm128<true,false,false,true,true><<<dim3(2,256), b256, 0, stream>>>(
      fq, wt + 917504, tr_b2, out, out, 32768, 256, 1024, 0);
}